// Round 17
// baseline (721.628 us; speedup 1.0000x reference)
//
#include <hip/hip_runtime.h>
#include <math.h>
#include <stdint.h>

typedef __attribute__((ext_vector_type(8))) short bf16x8;
typedef __attribute__((ext_vector_type(4))) float f32x4;

static __device__ __forceinline__ unsigned short f2bf(float f) {
    unsigned u = __builtin_bit_cast(unsigned, f);
    unsigned r = u + 0x7fffu + ((u >> 16) & 1u);   // RNE
    return (unsigned short)(r >> 16);
}
static __device__ __forceinline__ float bf2f(unsigned short h) {
    return __builtin_bit_cast(float, ((unsigned)h) << 16);
}
// async global->LDS, 16B per lane; lds dest = uniform base + lane*16
static __device__ __forceinline__ void gload_lds16(const void* g, void* l) {
    __builtin_amdgcn_global_load_lds((const __attribute__((address_space(1))) unsigned int*)g,
                                     (__attribute__((address_space(3))) unsigned int*)l, 16, 0, 0);
}

// ---------------------------------------------------------------------------
// gather pass1: x0b[t'][cc] (bf16) = src[bb][cc][u*5+v][y][x]
__global__ __launch_bounds__(256) void gather1(const float* __restrict__ src,
                                               unsigned short* __restrict__ x0, int W, int bb0) {
    int cct = blockIdx.x & 3, y = blockIdx.x >> 2;
    int n = blockIdx.y; int u = n / 5, v = n % 5;
    int lb = blockIdx.z, bb = bb0 + lb;
    __shared__ float tile[32][33];
    int tx = threadIdx.x & 31, tg = threadIdx.x >> 5;
    const float* s = src + (((size_t)(bb * 128 + cct * 32) * 25 + n) * 32 + y) * 32;
    #pragma unroll
    for (int i = 0; i < 4; i++) {
        int cl = tg + 8 * i;
        tile[cl][tx] = s[(size_t)cl * 25600 + tx];
    }
    __syncthreads();
    unsigned short* d = x0 + ((size_t)(u * 32 + y) * W + lb * 160 + v * 32) * 128 + cct * 32;
    #pragma unroll
    for (int i = 0; i < 4; i++) {
        int xx = tg + 8 * i;
        d[(size_t)xx * 128 + tx] = f2bf(tile[tx][xx]);
    }
}

// gather pass2
__global__ __launch_bounds__(256) void gather2(const float* __restrict__ src,
                                               unsigned short* __restrict__ x0, int W, int bb0) {
    int cct = blockIdx.x & 3, x = blockIdx.x >> 2;
    int n = blockIdx.y; int u = n / 5, v = n % 5;
    int lb = blockIdx.z, bb = bb0 + lb;
    __shared__ float tile[32][33];
    int tx = threadIdx.x & 31, tg = threadIdx.x >> 5;
    const float* s = src + (((size_t)(bb * 128 + cct * 32) * 25 + n) * 32) * 32 + x;
    #pragma unroll
    for (int i = 0; i < 4; i++) {
        int cl = tg + 8 * i;
        tile[cl][tx] = s[(size_t)cl * 25600 + tx * 32];
    }
    __syncthreads();
    unsigned short* d = x0 + ((size_t)(v * 32 + x) * W + lb * 160 + u * 32) * 128 + cct * 32;
    #pragma unroll
    for (int i = 0; i < 4; i++) {
        int yy = tg + 8 * i;
        d[(size_t)yy * 128 + tx] = f2bf(tile[tx][yy]);
    }
}

// ---------------------------------------------------------------------------
// conv weight repack: conv_w[co][ci][tap(9)] f32 -> wb[tap][co][ci] bf16
__global__ __launch_bounds__(256) void repack_w(const float* __restrict__ cw,
                                                unsigned short* __restrict__ wb) {
    int g = blockIdx.x * 256 + threadIdx.x;
    int co = g / 1152;
    int rem = g - co * 1152;
    int ci = rem / 9, tap = rem - ci * 9;
    wb[((size_t)tap * 128 + co) * 128 + ci] = f2bf(cw[g]);
}

// GEMM weights -> one bf16 buffer (layout preserved [N][K])
__global__ __launch_bounds__(256) void conv_weights(const float* __restrict__ Win,
                                                    const float* __restrict__ in_proj,
                                                    const float* __restrict__ attn_out_w,
                                                    const float* __restrict__ ff1,
                                                    const float* __restrict__ ff2,
                                                    const float* __restrict__ Wout,
                                                    unsigned short* __restrict__ wg) {
    int g = blockIdx.x * 256 + threadIdx.x;      // 589824 total
    float v;
    if      (g < 32768)  v = Win[g];
    else if (g < 229376) v = in_proj[g - 32768];
    else if (g < 294912) v = attn_out_w[g - 229376];
    else if (g < 425984) v = ff1[g - 294912];
    else if (g < 557056) v = ff2[g - 425984];
    else                 v = Wout[g - 557056];
    wg[g] = f2bf(v);
}

// ---------------------------------------------------------------------------
// LayerNorm over E=256, bf16 in -> bf16 out (f32 stats)
__global__ __launch_bounds__(256) void ln_bf16(const unsigned short* __restrict__ in,
                                               unsigned short* __restrict__ out,
                                               const float* __restrict__ w, const float* __restrict__ b) {
    int tok = blockIdx.x * 4 + (threadIdx.x >> 6);
    int lane = threadIdx.x & 63;
    ushort4 h4 = ((const ushort4*)(in + (size_t)tok * 256))[lane];
    float vx = bf2f(h4.x), vy = bf2f(h4.y), vz = bf2f(h4.z), vw = bf2f(h4.w);
    float s = vx + vy + vz + vw;
    #pragma unroll
    for (int off = 32; off > 0; off >>= 1) s += __shfl_xor(s, off);
    float mu = s * (1.0f / 256.0f);
    float dx = vx - mu, dy = vy - mu, dz = vz - mu, dw = vw - mu;
    float vs = dx * dx + dy * dy + dz * dz + dw * dw;
    #pragma unroll
    for (int off = 32; off > 0; off >>= 1) vs += __shfl_xor(vs, off);
    float inv = rsqrtf(vs * (1.0f / 256.0f) + 1e-5f);
    float4 wv = ((const float4*)w)[lane];
    float4 bv = ((const float4*)b)[lane];
    ushort4 o4;
    o4.x = f2bf(dx * inv * wv.x + bv.x);
    o4.y = f2bf(dy * inv * wv.y + bv.y);
    o4.z = f2bf(dz * inv * wv.z + bv.z);
    o4.w = f2bf(dw * inv * wv.w + bv.w);
    *(ushort4*)(out + (size_t)tok * 256 + lane * 4) = o4;
}

// ---------------------------------------------------------------------------
// XCD/L2-aware block remap (requires gridDim.x % 8 == 0)
static __device__ __forceinline__ void xcd_remap(int& bxi, int& byi) {
    int d = blockIdx.x + gridDim.x * blockIdx.y;
    int s = d & 7;
    unsigned j = (unsigned)(d >> 3);
    unsigned ny = gridDim.y;
    int gm8 = (int)(gridDim.x >> 3);
    bxi = s * gm8 + (int)(j / ny);
    byi = (int)(j % ny);
}

// ---------------------------------------------------------------------------
// GEMM core 64x64: BK=32, 2-buffer global_load_lds pipeline (round-12 best).
// LDS 16KB -> ~8 blocks/CU. 16B-slot swizzle slot ^= (row>>1)&3.
static __device__ __forceinline__ void gemm_core64(const unsigned short* __restrict__ X,
                                                   const unsigned short* __restrict__ Wt,
                                                   int bm, int bnrow, int K,
                                                   unsigned short (&As)[2][64 * 32],
                                                   unsigned short (&Bs)[2][64 * 32],
                                                   f32x4 (&acc)[2][2]) {
    const int tid = threadIdx.x;
    const int lane = tid & 63, w = tid >> 6;
    const int wm = (w >> 1) * 32, wn = (w & 1) * 32;
    const int lr = lane & 15, lq = lane >> 4;
    #pragma unroll
    for (int m = 0; m < 2; m++)
        #pragma unroll
        for (int n = 0; n < 2; n++)
            acc[m][n] = (f32x4){0.f, 0.f, 0.f, 0.f};

    const int srow = tid >> 2, sslot = tid & 3;
    const int ssl = sslot ^ ((srow >> 1) & 3);
    auto STAGE = [&](int bsel, int k0) {
        gload_lds16(X  + (size_t)(bm + srow) * K + k0 + ssl * 8,
                    &As[bsel][tid * 8]);
        gload_lds16(Wt + (size_t)(bnrow + srow) * K + k0 + ssl * 8,
                    &Bs[bsel][tid * 8]);
    };

    const int nt = K >> 5;
    STAGE(0, 0);
    __syncthreads();
    int cur = 0;
    for (int t = 0; t < nt; ++t) {
        if (t + 1 < nt) STAGE(cur ^ 1, (t + 1) << 5);
        const char* Ab = (const char*)As[cur];
        const char* Bb = (const char*)Bs[cur];
        bf16x8 af[2], bf[2];
        #pragma unroll
        for (int m = 0; m < 2; m++) {
            int row = wm + m * 16 + lr;
            af[m] = *(const bf16x8*)(Ab + row * 64 + ((lq * 16) ^ (((row >> 1) & 3) << 4)));
        }
        #pragma unroll
        for (int n = 0; n < 2; n++) {
            int row = wn + n * 16 + lr;
            bf[n] = *(const bf16x8*)(Bb + row * 64 + ((lq * 16) ^ (((row >> 1) & 3) << 4)));
        }
        #pragma unroll
        for (int m = 0; m < 2; m++)
            #pragma unroll
            for (int n = 0; n < 2; n++)
                acc[m][n] = __builtin_amdgcn_mfma_f32_16x16x32_bf16(af[m], bf[n], acc[m][n], 0, 0, 0);
        if (t + 1 < nt) __syncthreads();
        cur ^= 1;
    }
}

// general GEMM: Y = X @ Wt^T (+Rb) (relu?), spass=1/2 fused scatter epilogue
__global__ __launch_bounds__(256) void gemm_bf16(const unsigned short* __restrict__ X,
                                                 const unsigned short* __restrict__ Wt,
                                                 unsigned short* __restrict__ Yb,
                                                 const unsigned short* __restrict__ Rb,
                                                 int N, int K, int relu, int spass, int W) {
    __shared__ unsigned short As[2][64 * 32];
    __shared__ unsigned short Bs[2][64 * 32];
    int bxi, byi;
    xcd_remap(bxi, byi);
    const int bm = bxi * 64, bn = byi * 64;
    f32x4 acc[2][2];
    gemm_core64(X, Wt, bm, bn, K, As, Bs, acc);

    const int lane = threadIdx.x & 63, w = threadIdx.x >> 6;
    const int wm = (w >> 1) * 32, wn = (w & 1) * 32;
    const int lr = lane & 15, lq = lane >> 4;
    #pragma unroll
    for (int m = 0; m < 2; m++) {
        #pragma unroll
        for (int r = 0; r < 4; r++) {
            int row = bm + wm + m * 16 + lq * 4 + r;
            size_t base;
            if (spass == 0) {
                base = (size_t)row * N;
            } else {
                int l = row / W, c = row - l * W;
                int lb = (c >= 160) ? 1 : 0, sp = c - lb * 160;
                int sl_, pix;
                if (spass == 1) { int u = l >> 5, y = l & 31, v = sp >> 5, x = sp & 31;
                                  sl_ = lb * 25 + u * 5 + v; pix = y * 32 + x; }
                else            { int v = l >> 5, x = l & 31, u = sp >> 5, y = sp & 31;
                                  sl_ = lb * 25 + u * 5 + v; pix = y * 32 + x; }
                base = ((size_t)sl_ * 1024 + pix) * 128;
            }
            #pragma unroll
            for (int n = 0; n < 2; n++) {
                int col = bn + wn + n * 16 + lr;
                float val = acc[m][n][r];
                if (Rb) val += bf2f(Rb[(size_t)row * N + col]);
                if (relu) val = fmaxf(val, 0.0f);
                Yb[base + col] = f2bf(val);
            }
        }
    }
}

// fused qk+v GEMM (64x64 tiles): in_proj rows [0..767] = [Wq;Wk;Wv], K=256.
__global__ __launch_bounds__(256) void gemm_qkv(const unsigned short* __restrict__ tn,
                                                const unsigned short* __restrict__ tok,
                                                const unsigned short* __restrict__ Wqkv,
                                                unsigned short* __restrict__ QK,
                                                unsigned short* __restrict__ V) {
    __shared__ unsigned short As[2][64 * 32];
    __shared__ unsigned short Bs[2][64 * 32];
    int bxi, by;
    xcd_remap(bxi, by);
    const int bm = bxi * 64;
    const unsigned short* X = (by < 8) ? tn : tok;
    f32x4 acc[2][2];
    gemm_core64(X, Wqkv, bm, by * 64, 256, As, Bs, acc);

    unsigned short* Yb = (by < 8) ? QK : V;
    const int N = (by < 8) ? 512 : 256;
    const int bn = (by < 8) ? by * 64 : (by - 8) * 64;
    const int lane = threadIdx.x & 63, w = threadIdx.x >> 6;
    const int wm = (w >> 1) * 32, wn = (w & 1) * 32;
    const int lr = lane & 15, lq = lane >> 4;
    #pragma unroll
    for (int m = 0; m < 2; m++) {
        #pragma unroll
        for (int r = 0; r < 4; r++) {
            int row = bm + wm + m * 16 + lq * 4 + r;
            #pragma unroll
            for (int n = 0; n < 2; n++) {
                int col = bn + wn + n * 16 + lr;
                Yb[(size_t)row * N + col] = f2bf(acc[m][n][r]);
            }
        }
    }
}

// ---------------------------------------------------------------------------
// Fused FFN v4: R += relu(X @ W1^T) @ W2^T, in-place on R (bf16 residual).
// Weight fragments read DIRECTLY global->VGPR (16B contiguous rows; all 800
// blocks read the same 1MB -> L2-hot broadcast). No weight LDS, no staging
// barriers: LDS = Hs 8KB only, 2 barriers/chunk; gemm1(hk+1) overlaps
// gemm2(hk). MFMA order per accumulator identical to v2 -> same rounding.
__global__ __launch_bounds__(256) void ffn_fused(const unsigned short* __restrict__ X,
                                                 const unsigned short* __restrict__ W1,
                                                 const unsigned short* __restrict__ W2,
                                                 unsigned short* __restrict__ R) {
    __shared__ unsigned short Hs[64 * 64];    // 8 KB, row 128B, slot ^= row&7
    const int tid = threadIdx.x;
    const int lane = tid & 63, w = tid >> 6;
    const int lr = lane & 15, lq = lane >> 4;
    const int thm = (w >> 1) * 32;            // token rows for gemm2 A
    const int thb = (w & 1) * 32;             // token rows for gemm1 B
    const int hh  = (w >> 1) * 32;            // hidden rows for gemm1 A
    const int wn2 = (w & 1) * 128;            // out cols (gemm2)
    const int bm = blockIdx.x * 64;

    f32x4 acc_o[2][8];
    #pragma unroll
    for (int m = 0; m < 2; m++)
        #pragma unroll
        for (int nt = 0; nt < 8; nt++)
            acc_o[m][nt] = (f32x4){0.f, 0.f, 0.f, 0.f};

    for (int hk = 0; hk < 8; hk++) {
        // gemm1: hidden chunk [64 hid][64 tok], K=256; all operands from global
        f32x4 acc1[2][2];
        #pragma unroll
        for (int mh = 0; mh < 2; mh++)
            #pragma unroll
            for (int nt = 0; nt < 2; nt++)
                acc1[mh][nt] = (f32x4){0.f, 0.f, 0.f, 0.f};
        #pragma unroll
        for (int ks = 0; ks < 8; ks++) {
            bf16x8 w1f[2], xtf[2];
            #pragma unroll
            for (int mh = 0; mh < 2; mh++)
                w1f[mh] = *(const bf16x8*)(W1 + (size_t)(hk * 64 + hh + mh * 16 + lr) * 256 + ks * 32 + lq * 8);
            #pragma unroll
            for (int nt = 0; nt < 2; nt++)
                xtf[nt] = *(const bf16x8*)(X + (size_t)(bm + thb + nt * 16 + lr) * 256 + ks * 32 + lq * 8);
            #pragma unroll
            for (int mh = 0; mh < 2; mh++)
                #pragma unroll
                for (int nt = 0; nt < 2; nt++)
                    acc1[mh][nt] = __builtin_amdgcn_mfma_f32_16x16x32_bf16(w1f[mh], xtf[nt], acc1[mh][nt], 0, 0, 0);
        }
        if (hk) __syncthreads();              // prev gemm2's Hs reads done
        // relu -> bf16 -> Hs[tok][hid], packed 8B (D: row=hidden, col=token)
        #pragma unroll
        for (int mh = 0; mh < 2; mh++)
            #pragma unroll
            for (int nt = 0; nt < 2; nt++) {
                int hid0 = hh + mh * 16 + lq * 4;
                int tokr = thb + nt * 16 + lr;
                ushort4 pk;
                pk.x = f2bf(fmaxf(acc1[mh][nt][0], 0.0f));
                pk.y = f2bf(fmaxf(acc1[mh][nt][1], 0.0f));
                pk.z = f2bf(fmaxf(acc1[mh][nt][2], 0.0f));
                pk.w = f2bf(fmaxf(acc1[mh][nt][3], 0.0f));
                *(ushort4*)((char*)Hs + tokr * 128 +
                            (((hid0 >> 3) ^ (tokr & 7)) << 4) + (hid0 & 7) * 2) = pk;
            }
        __syncthreads();                      // Hs visible

        // gemm2: out[64][256] += Hs[64][64] @ W2c^T, k=64; W2 from global
        #pragma unroll
        for (int ks = 0; ks < 2; ks++) {
            int slot = ks * 4 + lq;
            bf16x8 af2[2];
            #pragma unroll
            for (int m = 0; m < 2; m++) {
                int trow = thm + m * 16 + lr;
                af2[m] = *(const bf16x8*)((const char*)Hs + trow * 128 + ((slot ^ (trow & 7)) << 4));
            }
            #pragma unroll
            for (int nt = 0; nt < 8; nt++) {
                bf16x8 b2 = *(const bf16x8*)(W2 + (size_t)(wn2 + nt * 16 + lr) * 512 + hk * 64 + ks * 32 + lq * 8);
                #pragma unroll
                for (int m = 0; m < 2; m++)
                    acc_o[m][nt] = __builtin_amdgcn_mfma_f32_16x16x32_bf16(af2[m], b2, acc_o[m][nt], 0, 0, 0);
            }
        }
    }
    // epilogue: in-place residual add on R
    #pragma unroll
    for (int m = 0; m < 2; m++)
        #pragma unroll
        for (int nt = 0; nt < 8; nt++)
            #pragma unroll
            for (int r = 0; r < 4; r++) {
                int row = bm + thm + m * 16 + lq * 4 + r;
                int col = wn2 + nt * 16 + lr;
                size_t off = (size_t)row * 256 + col;
                R[off] = f2bf(acc_o[m][nt][r] + bf2f(R[off]));
            }
}

// ---------------------------------------------------------------------------
// V transpose: Vtok[t][256] bf16 -> Vt[h][col][d(32)][l(160)] bf16
__global__ __launch_bounds__(256) void vtrans(const unsigned short* __restrict__ vtok,
                                              unsigned short* __restrict__ vt, int W) {
    const int col = blockIdx.x, h = blockIdx.y;
    __shared__ unsigned short t[160][34];
    const int tid = threadIdx.x;
    for (int i = tid; i < 160 * 16; i += 256) {
        int l = i >> 4, dp = i & 15;
        unsigned v = *(const unsigned*)(vtok + ((size_t)l * W + col) * 256 + h * 32 + dp * 2);
        *(unsigned*)&t[l][dp * 2] = v;
    }
    __syncthreads();
    unsigned short* dst = vt + (((size_t)h * W + col) * 32) * 160;
    for (int i = tid; i < 32 * 160; i += 256) {
        int d = i / 160, l = i - d * 160;
        dst[i] = t[l][d];
    }
}

// ---------------------------------------------------------------------------
// MFMA attention (verified round 4/5), bf16 in/out
__global__ __launch_bounds__(64) void attn_mfma(const unsigned short* __restrict__ qk,
                                                const unsigned short* __restrict__ vt,
                                                unsigned short* __restrict__ o, int W) {
    const int col = blockIdx.x;
    const int h = blockIdx.y;
    const int lane = threadIdx.x;
    const int lr = lane & 15, lq = lane >> 4;
    __shared__ __align__(16) unsigned short P_lds[16][168];

    bf16x8 kf[10];
    #pragma unroll
    for (int m = 0; m < 10; m++) {
        size_t t = (size_t)(m * 16 + lr) * W + col;
        kf[m] = *(const bf16x8*)(qk + t * 512 + 256 + h * 32 + lq * 8);
    }
    const unsigned short* vbase = vt + (((size_t)h * W + col) * 32) * 160;
    bf16x8 vf[2][5];
    #pragma unroll
    for (int md = 0; md < 2; md++)
        #pragma unroll
        for (int c = 0; c < 5; c++)
            vf[md][c] = *(const bf16x8*)(vbase + (size_t)(md * 16 + lr) * 160 + c * 32 + lq * 8);

    const float scale = 0.17677669529663687f;
    for (int n = 0; n < 10; n++) {
        const int q = n * 16 + lr;
        bf16x8 qf = *(const bf16x8*)(qk + ((size_t)q * W + col) * 512 + h * 32 + lq * 8);
        f32x4 p[10];
        #pragma unroll
        for (int m = 0; m < 10; m++)
            p[m] = __builtin_amdgcn_mfma_f32_16x16x32_bf16(kf[m], qf, (f32x4){0.f,0.f,0.f,0.f}, 0, 0, 0);
        const int b = lq * 4 - ((n & 1) * 16 + lr);
        float mx = -1e30f;
        #pragma unroll
        for (int m = 0; m < 10; m++) {
            #pragma unroll
            for (int r = 0; r < 4; r++) {
                int dd = b + (m & 1) * 16 + r;
                float s = ((unsigned)(dd + 5) <= 10u) ? p[m][r] : -1e30f;
                p[m][r] = s;
                mx = fmaxf(mx, s);
            }
        }
        mx = fmaxf(mx, __shfl_xor(mx, 16));
        mx = fmaxf(mx, __shfl_xor(mx, 32));
        float sum = 0.f;
        #pragma unroll
        for (int m = 0; m < 10; m++) {
            #pragma unroll
            for (int r = 0; r < 4; r++) {
                float e = __expf((p[m][r] - mx) * scale);
                p[m][r] = e;
                sum += e;
            }
        }
        sum += __shfl_xor(sum, 16);
        sum += __shfl_xor(sum, 32);
        #pragma unroll
        for (int m = 0; m < 10; m++) {
            ushort4 pk;
            pk.x = f2bf(p[m][0]); pk.y = f2bf(p[m][1]);
            pk.z = f2bf(p[m][2]); pk.w = f2bf(p[m][3]);
            *(ushort4*)&P_lds[lr][m * 16 + lq * 4] = pk;
        }
        f32x4 oa0 = (f32x4){0.f,0.f,0.f,0.f}, oa1 = (f32x4){0.f,0.f,0.f,0.f};
        #pragma unroll
        for (int c = 0; c < 5; c++) {
            bf16x8 pf = *(const bf16x8*)&P_lds[lr][c * 32 + lq * 8];
            oa0 = __builtin_amdgcn_mfma_f32_16x16x32_bf16(vf[0][c], pf, oa0, 0, 0, 0);
            oa1 = __builtin_amdgcn_mfma_f32_16x16x32_bf16(vf[1][c], pf, oa1, 0, 0, 0);
        }
        const float inv = 1.0f / sum;
        unsigned short* op = o + ((size_t)q * W + col) * 256 + h * 32;
        ushort4 s0, s1;
        s0.x = f2bf(oa0[0] * inv); s0.y = f2bf(oa0[1] * inv);
        s0.z = f2bf(oa0[2] * inv); s0.w = f2bf(oa0[3] * inv);
        s1.x = f2bf(oa1[0] * inv); s1.y = f2bf(oa1[1] * inv);
        s1.z = f2bf(oa1[2] * inv); s1.w = f2bf(oa1[3] * inv);
        *(ushort4*)(op + lq * 4)      = s0;
        *(ushort4*)(op + 16 + lq * 4) = s1;
    }
}

// ---------------------------------------------------------------------------
// conv as implicit MFMA GEMM (verified round 3)
__global__ __launch_bounds__(256) void conv_mfma(const unsigned short* __restrict__ xp,
                                                 const unsigned short* __restrict__ wb,
                                                 const float* __restrict__ res,
                                                 float* __restrict__ out, int bb0) {
    const int ptile = blockIdx.x;
    const int slice = blockIdx.y;
    const int lb = slice / 25, n = slice % 25;
    const int bb = bb0 + lb;
    const int y0 = ptile * 4;
    __shared__ unsigned short As[128 * 64];
    __shared__ unsigned short Bs[128 * 64];
    const int tid = threadIdx.x;
    const int lane = tid & 63, w = tid >> 6;
    const int wm = (w >> 1) * 64;
    const int wn = (w & 1) * 64;
    const int lr = lane & 15, lq = lane >> 4;
    const unsigned short* xs = xp + (size_t)slice * 1024 * 128;
    f32x4 acc[4][4];
    #pragma unroll
    for (int m = 0; m < 4; m++)
        #pragma unroll
        for (int nn = 0; nn < 4; nn++)
            acc[m][nn] = (f32x4){0.f, 0.f, 0.f, 0.f};

    for (int tap = 0; tap < 9; tap++) {
        const int dy = tap / 3 - 1, dx = tap % 3 - 1;
        for (int c0 = 0; c0 < 128; c0 += 64) {
            #pragma unroll
            for (int i = 0; i < 4; i++) {
                int id = tid + 256 * i;
                int row = id >> 3, cg = id & 7;
                int py = y0 + (row >> 5) + dy;
                int px = (row & 31) + dx;
                uint4 v = {0u, 0u, 0u, 0u};
                if ((unsigned)py < 32u && (unsigned)px < 32u)
                    v = *(const uint4*)(xs + ((size_t)(py * 32 + px) * 128 + c0 + cg * 8));
                int boff = row * 128 + ((cg * 16) ^ ((row & 7) << 4));
                *(uint4*)((char*)As + boff) = v;
            }
            #pragma unroll
            for (int i = 0; i < 4; i++) {
                int id = tid + 256 * i;
                int row = id >> 3, cg = id & 7;
                uint4 v = *(const uint4*)(wb + (((size_t)tap * 128 + row) * 128 + c0 + cg * 8));
                int boff = row * 128 + ((cg * 16) ^ ((row & 7) << 4));
                *(uint4*)((char*)Bs + boff) = v;
            }
            __syncthreads();
            #pragma unroll
            for (int ks = 0; ks < 2; ks++) {
                bf16x8 wf[4], xf[4];
                #pragma unroll
                for (int m = 0; m < 4; m++) {
                    int row = wm + m * 16 + lr;
                    int boff = row * 128 + ((ks * 64 + lq * 16) ^ ((row & 7) << 4));
                    wf[m] = *(const bf16x8*)((const char*)Bs + boff);
                }
                #pragma unroll
                for (int nn = 0; nn < 4; nn++) {
                    int row = wn + nn * 16 + lr;
                    int boff = row * 128 + ((ks * 64 + lq * 16) ^ ((row & 7) << 4));
                    xf[nn] = *(const bf16x8*)((const char*)As + boff);
                }
                #pragma unroll
                for (int m = 0; m < 4; m++)
                    #pragma unroll
                    for (int nn = 0; nn < 4; nn++)
                        acc[m][nn] = __builtin_amdgcn_mfma_f32_16x16x32_bf16(wf[m], xf[nn], acc[m][nn], 0, 0, 0);
            }
            __syncthreads();
        }
    }
    #pragma unroll
    for (int m = 0; m < 4; m++) {
        int co0 = wm + m * 16 + lq * 4;
        #pragma unroll
        for (int r = 0; r < 4; r++) {
            size_t rowoff = (((size_t)(bb * 128 + co0 + r) * 25 + n) * 1024) + ptile * 128;
            #pragma unroll
            for (int nn = 0; nn < 4; nn++) {
                int pix = wn + nn * 16 + lr;
                out[rowoff + pix] = acc[m][nn][r] + res[rowoff + pix];
            }
        }
    }
}

// ---------------------------------------------------------------------------
extern "C" void kernel_launch(void* const* d_in, const int* in_sizes, int n_in,
                              void* d_out, int out_size, void* d_ws, size_t ws_size,
                              hipStream_t stream) {
    (void)in_sizes; (void)n_in; (void)out_size;
    const float* buffer     = (const float*)d_in[0];
    const float* Win        = (const float*)d_in[1];
    const float* ln_w       = (const float*)d_in[2];
    const float* ln_b       = (const float*)d_in[3];
    const float* in_proj    = (const float*)d_in[4];
    const float* attn_out_w = (const float*)d_in[5];
    const float* ffn_ln_w   = (const float*)d_in[6];
    const float* ffn_ln_b   = (const float*)d_in[7];
    const float* ff1        = (const float*)d_in[8];
    const float* ff2        = (const float*)d_in[9];
    const float* Wout       = (const float*)d_in[10];
    const float* conv_w     = (const float*)d_in[11];
    float* out = (float*)d_out;
    float* ws  = (float*)d_ws;

    const size_t need2 = ((size_t)51200 * 960 + 368640) * 4;
    int NBB = (ws_size >= need2) ? 2 : 1;
    const int W = NBB * 160;
    const size_t T = (size_t)NBB * 25600;

    // layout (float-slot offsets); all bf16
    unsigned short* x0b   = (unsigned short*)ws;                 // T*128 bf16
    unsigned short* Abf   = (unsigned short*)(ws + T * 64);      // T*256 bf16 residual
    unsigned short* tnb   = (unsigned short*)(ws + T * 192);     // T*256 bf16
    float*          C     = ws + T * 320;                        // T*512 fl region
    unsigned short* QKtok = (unsigned short*)C;                  // T*512 bf16
    unsigned short* Vtok  = (unsigned short*)(C + T * 256);      // T*256 bf16
    unsigned short* Vt    = (unsigned short*)(C + T * 384);      // T*256 bf16
    unsigned short* xp    = (unsigned short*)C;                  // T*128 bf16
    unsigned short* Db    = (unsigned short*)(ws + T * 832);     // T*256 bf16
    unsigned short* wg    = (unsigned short*)(ws + T * 960);     // 589824 bf16
    unsigned short* wb    = (unsigned short*)(ws + T * 960 + 294912); // 147456 bf16

    const unsigned short* Winb  = wg;
    const unsigned short* Wqkvb = wg + 32768;            // 768 rows: [Wq;Wk;Wv]
    const unsigned short* Waob  = wg + 229376;
    const unsigned short* Wff1b = wg + 294912;
    const unsigned short* Wff2b = wg + 425984;
    const unsigned short* Woutb = wg + 557056;

    const int GM64 = (int)(T / 64);      // 800 (or 400), % 8 == 0

    conv_weights<<<2304, 256, 0, stream>>>(Win, in_proj, attn_out_w, ff1, ff2, Wout, wg);
    repack_w<<<576, 256, 0, stream>>>(conv_w, wb);

    for (int pass = 0; pass < 2; pass++) {
        const float* src = (pass == 0) ? buffer : out;
        for (int bb0 = 0; bb0 < 2; bb0 += NBB) {
            if (pass == 0) gather1<<<dim3(128, 25, NBB), 256, 0, stream>>>(src, x0b, W, bb0);
            else           gather2<<<dim3(128, 25, NBB), 256, 0, stream>>>(src, x0b, W, bb0);

            // tok = x0 @ Win^T (K=128) -> Abf
            gemm_bf16<<<dim3(GM64, 4), 256, 0, stream>>>(x0b, Winb, Abf, nullptr, 256, 128, 0, 0, W);
            ln_bf16<<<(int)(T / 4), 256, 0, stream>>>(Abf, tnb, ln_w, ln_b);
            // fused qk (tn) + v (tok) projections, K=256
            gemm_qkv<<<dim3(GM64, 12), 256, 0, stream>>>(tnb, Abf, Wqkvb, QKtok, Vtok);
            vtrans<<<dim3(W, 8), 256, 0, stream>>>(Vtok, Vt, W);
            attn_mfma<<<dim3(W, 8), 64, 0, stream>>>(QKtok, Vt, Db, W);
            // tok += ob @ attn_out_w^T  (in-place bf16 residual)
            gemm_bf16<<<dim3(GM64, 4), 256, 0, stream>>>(Db, Waob, Abf, Abf, 256, 256, 0, 0, W);
            ln_bf16<<<(int)(T / 4), 256, 0, stream>>>(Abf, tnb, ffn_ln_w, ffn_ln_b);
            // fused FFN: Abf += relu(tnb @ ff1^T) @ ff2^T
            ffn_fused<<<GM64, 256, 0, stream>>>(tnb, Wff1b, Wff2b, Abf);
            // ot = tok @ Wout^T (N=128) -> fused scatter into xp (pixel-major)
            gemm_bf16<<<dim3(GM64, 2), 256, 0, stream>>>(Abf, Woutb, xp, nullptr, 128, 256, 0, pass + 1, W);

            conv_mfma<<<dim3(8, NBB * 25), 256, 0, stream>>>(
                xp, wb, (pass == 0) ? buffer : (const float*)out, out, bb0);
        }
    }
}

// Round 18
// 559.571 us; speedup vs baseline: 1.2896x; 1.2896x over previous
//
#include <hip/hip_runtime.h>
#include <math.h>
#include <stdint.h>

typedef __attribute__((ext_vector_type(8))) short bf16x8;
typedef __attribute__((ext_vector_type(4))) float f32x4;

static __device__ __forceinline__ unsigned short f2bf(float f) {
    unsigned u = __builtin_bit_cast(unsigned, f);
    unsigned r = u + 0x7fffu + ((u >> 16) & 1u);   // RNE
    return (unsigned short)(r >> 16);
}
static __device__ __forceinline__ float bf2f(unsigned short h) {
    return __builtin_bit_cast(float, ((unsigned)h) << 16);
}
// async global->LDS, 16B per lane; lds dest = uniform base + lane*16
static __device__ __forceinline__ void gload_lds16(const void* g, void* l) {
    __builtin_amdgcn_global_load_lds((const __attribute__((address_space(1))) unsigned int*)g,
                                     (__attribute__((address_space(3))) unsigned int*)l, 16, 0, 0);
}

// ---------------------------------------------------------------------------
// gather pass1: x0b[t'][cc] (bf16) = src[bb][cc][u*5+v][y][x]
__global__ __launch_bounds__(256) void gather1(const float* __restrict__ src,
                                               unsigned short* __restrict__ x0, int W, int bb0) {
    int cct = blockIdx.x & 3, y = blockIdx.x >> 2;
    int n = blockIdx.y; int u = n / 5, v = n % 5;
    int lb = blockIdx.z, bb = bb0 + lb;
    __shared__ float tile[32][33];
    int tx = threadIdx.x & 31, tg = threadIdx.x >> 5;
    const float* s = src + (((size_t)(bb * 128 + cct * 32) * 25 + n) * 32 + y) * 32;
    #pragma unroll
    for (int i = 0; i < 4; i++) {
        int cl = tg + 8 * i;
        tile[cl][tx] = s[(size_t)cl * 25600 + tx];
    }
    __syncthreads();
    unsigned short* d = x0 + ((size_t)(u * 32 + y) * W + lb * 160 + v * 32) * 128 + cct * 32;
    #pragma unroll
    for (int i = 0; i < 4; i++) {
        int xx = tg + 8 * i;
        d[(size_t)xx * 128 + tx] = f2bf(tile[tx][xx]);
    }
}

// gather pass2
__global__ __launch_bounds__(256) void gather2(const float* __restrict__ src,
                                               unsigned short* __restrict__ x0, int W, int bb0) {
    int cct = blockIdx.x & 3, x = blockIdx.x >> 2;
    int n = blockIdx.y; int u = n / 5, v = n % 5;
    int lb = blockIdx.z, bb = bb0 + lb;
    __shared__ float tile[32][33];
    int tx = threadIdx.x & 31, tg = threadIdx.x >> 5;
    const float* s = src + (((size_t)(bb * 128 + cct * 32) * 25 + n) * 32) * 32 + x;
    #pragma unroll
    for (int i = 0; i < 4; i++) {
        int cl = tg + 8 * i;
        tile[cl][tx] = s[(size_t)cl * 25600 + tx * 32];
    }
    __syncthreads();
    unsigned short* d = x0 + ((size_t)(v * 32 + x) * W + lb * 160 + u * 32) * 128 + cct * 32;
    #pragma unroll
    for (int i = 0; i < 4; i++) {
        int yy = tg + 8 * i;
        d[(size_t)yy * 128 + tx] = f2bf(tile[tx][yy]);
    }
}

// ---------------------------------------------------------------------------
// conv weight repack: conv_w[co][ci][tap(9)] f32 -> wb[tap][co][ci] bf16
__global__ __launch_bounds__(256) void repack_w(const float* __restrict__ cw,
                                                unsigned short* __restrict__ wb) {
    int g = blockIdx.x * 256 + threadIdx.x;
    int co = g / 1152;
    int rem = g - co * 1152;
    int ci = rem / 9, tap = rem - ci * 9;
    wb[((size_t)tap * 128 + co) * 128 + ci] = f2bf(cw[g]);
}

// GEMM weights -> one bf16 buffer (layout preserved [N][K])
__global__ __launch_bounds__(256) void conv_weights(const float* __restrict__ Win,
                                                    const float* __restrict__ in_proj,
                                                    const float* __restrict__ attn_out_w,
                                                    const float* __restrict__ ff1,
                                                    const float* __restrict__ ff2,
                                                    const float* __restrict__ Wout,
                                                    unsigned short* __restrict__ wg) {
    int g = blockIdx.x * 256 + threadIdx.x;      // 589824 total
    float v;
    if      (g < 32768)  v = Win[g];
    else if (g < 229376) v = in_proj[g - 32768];
    else if (g < 294912) v = attn_out_w[g - 229376];
    else if (g < 425984) v = ff1[g - 294912];
    else if (g < 557056) v = ff2[g - 425984];
    else                 v = Wout[g - 557056];
    wg[g] = f2bf(v);
}

// ---------------------------------------------------------------------------
// LayerNorm over E=256, bf16 in -> bf16 out (f32 stats)
__global__ __launch_bounds__(256) void ln_bf16(const unsigned short* __restrict__ in,
                                               unsigned short* __restrict__ out,
                                               const float* __restrict__ w, const float* __restrict__ b) {
    int tok = blockIdx.x * 4 + (threadIdx.x >> 6);
    int lane = threadIdx.x & 63;
    ushort4 h4 = ((const ushort4*)(in + (size_t)tok * 256))[lane];
    float vx = bf2f(h4.x), vy = bf2f(h4.y), vz = bf2f(h4.z), vw = bf2f(h4.w);
    float s = vx + vy + vz + vw;
    #pragma unroll
    for (int off = 32; off > 0; off >>= 1) s += __shfl_xor(s, off);
    float mu = s * (1.0f / 256.0f);
    float dx = vx - mu, dy = vy - mu, dz = vz - mu, dw = vw - mu;
    float vs = dx * dx + dy * dy + dz * dz + dw * dw;
    #pragma unroll
    for (int off = 32; off > 0; off >>= 1) vs += __shfl_xor(vs, off);
    float inv = rsqrtf(vs * (1.0f / 256.0f) + 1e-5f);
    float4 wv = ((const float4*)w)[lane];
    float4 bv = ((const float4*)b)[lane];
    ushort4 o4;
    o4.x = f2bf(dx * inv * wv.x + bv.x);
    o4.y = f2bf(dy * inv * wv.y + bv.y);
    o4.z = f2bf(dz * inv * wv.z + bv.z);
    o4.w = f2bf(dw * inv * wv.w + bv.w);
    *(ushort4*)(out + (size_t)tok * 256 + lane * 4) = o4;
}

// ---------------------------------------------------------------------------
// XCD/L2-aware block remap (requires gridDim.x % 8 == 0)
static __device__ __forceinline__ void xcd_remap(int& bxi, int& byi) {
    int d = blockIdx.x + gridDim.x * blockIdx.y;
    int s = d & 7;
    unsigned j = (unsigned)(d >> 3);
    unsigned ny = gridDim.y;
    int gm8 = (int)(gridDim.x >> 3);
    bxi = s * gm8 + (int)(j / ny);
    byi = (int)(j % ny);
}

// ---------------------------------------------------------------------------
// GEMM core 64x64: BK=32, 2-buffer global_load_lds pipeline (round-12 best).
// LDS 16KB -> ~8 blocks/CU. 16B-slot swizzle slot ^= (row>>1)&3.
static __device__ __forceinline__ void gemm_core64(const unsigned short* __restrict__ X,
                                                   const unsigned short* __restrict__ Wt,
                                                   int bm, int bnrow, int K,
                                                   unsigned short (&As)[2][64 * 32],
                                                   unsigned short (&Bs)[2][64 * 32],
                                                   f32x4 (&acc)[2][2]) {
    const int tid = threadIdx.x;
    const int lane = tid & 63, w = tid >> 6;
    const int wm = (w >> 1) * 32, wn = (w & 1) * 32;
    const int lr = lane & 15, lq = lane >> 4;
    #pragma unroll
    for (int m = 0; m < 2; m++)
        #pragma unroll
        for (int n = 0; n < 2; n++)
            acc[m][n] = (f32x4){0.f, 0.f, 0.f, 0.f};

    const int srow = tid >> 2, sslot = tid & 3;
    const int ssl = sslot ^ ((srow >> 1) & 3);
    auto STAGE = [&](int bsel, int k0) {
        gload_lds16(X  + (size_t)(bm + srow) * K + k0 + ssl * 8,
                    &As[bsel][tid * 8]);
        gload_lds16(Wt + (size_t)(bnrow + srow) * K + k0 + ssl * 8,
                    &Bs[bsel][tid * 8]);
    };

    const int nt = K >> 5;
    STAGE(0, 0);
    __syncthreads();
    int cur = 0;
    for (int t = 0; t < nt; ++t) {
        if (t + 1 < nt) STAGE(cur ^ 1, (t + 1) << 5);
        const char* Ab = (const char*)As[cur];
        const char* Bb = (const char*)Bs[cur];
        bf16x8 af[2], bf[2];
        #pragma unroll
        for (int m = 0; m < 2; m++) {
            int row = wm + m * 16 + lr;
            af[m] = *(const bf16x8*)(Ab + row * 64 + ((lq * 16) ^ (((row >> 1) & 3) << 4)));
        }
        #pragma unroll
        for (int n = 0; n < 2; n++) {
            int row = wn + n * 16 + lr;
            bf[n] = *(const bf16x8*)(Bb + row * 64 + ((lq * 16) ^ (((row >> 1) & 3) << 4)));
        }
        #pragma unroll
        for (int m = 0; m < 2; m++)
            #pragma unroll
            for (int n = 0; n < 2; n++)
                acc[m][n] = __builtin_amdgcn_mfma_f32_16x16x32_bf16(af[m], bf[n], acc[m][n], 0, 0, 0);
        if (t + 1 < nt) __syncthreads();
        cur ^= 1;
    }
}

// general GEMM: Y = X @ Wt^T (+Rb) (relu?), spass=1/2 fused scatter epilogue
__global__ __launch_bounds__(256) void gemm_bf16(const unsigned short* __restrict__ X,
                                                 const unsigned short* __restrict__ Wt,
                                                 unsigned short* __restrict__ Yb,
                                                 const unsigned short* __restrict__ Rb,
                                                 int N, int K, int relu, int spass, int W) {
    __shared__ unsigned short As[2][64 * 32];
    __shared__ unsigned short Bs[2][64 * 32];
    int bxi, byi;
    xcd_remap(bxi, byi);
    const int bm = bxi * 64, bn = byi * 64;
    f32x4 acc[2][2];
    gemm_core64(X, Wt, bm, bn, K, As, Bs, acc);

    const int lane = threadIdx.x & 63, w = threadIdx.x >> 6;
    const int wm = (w >> 1) * 32, wn = (w & 1) * 32;
    const int lr = lane & 15, lq = lane >> 4;
    #pragma unroll
    for (int m = 0; m < 2; m++) {
        #pragma unroll
        for (int r = 0; r < 4; r++) {
            int row = bm + wm + m * 16 + lq * 4 + r;
            size_t base;
            if (spass == 0) {
                base = (size_t)row * N;
            } else {
                int l = row / W, c = row - l * W;
                int lb = (c >= 160) ? 1 : 0, sp = c - lb * 160;
                int sl_, pix;
                if (spass == 1) { int u = l >> 5, y = l & 31, v = sp >> 5, x = sp & 31;
                                  sl_ = lb * 25 + u * 5 + v; pix = y * 32 + x; }
                else            { int v = l >> 5, x = l & 31, u = sp >> 5, y = sp & 31;
                                  sl_ = lb * 25 + u * 5 + v; pix = y * 32 + x; }
                base = ((size_t)sl_ * 1024 + pix) * 128;
            }
            #pragma unroll
            for (int n = 0; n < 2; n++) {
                int col = bn + wn + n * 16 + lr;
                float val = acc[m][n][r];
                if (Rb) val += bf2f(Rb[(size_t)row * N + col]);
                if (relu) val = fmaxf(val, 0.0f);
                Yb[base + col] = f2bf(val);
            }
        }
    }
}

// fused qk+v GEMM (64x64 tiles): in_proj rows [0..767] = [Wq;Wk;Wv], K=256.
__global__ __launch_bounds__(256) void gemm_qkv(const unsigned short* __restrict__ tn,
                                                const unsigned short* __restrict__ tok,
                                                const unsigned short* __restrict__ Wqkv,
                                                unsigned short* __restrict__ QK,
                                                unsigned short* __restrict__ V) {
    __shared__ unsigned short As[2][64 * 32];
    __shared__ unsigned short Bs[2][64 * 32];
    int bxi, by;
    xcd_remap(bxi, by);
    const int bm = bxi * 64;
    const unsigned short* X = (by < 8) ? tn : tok;
    f32x4 acc[2][2];
    gemm_core64(X, Wqkv, bm, by * 64, 256, As, Bs, acc);

    unsigned short* Yb = (by < 8) ? QK : V;
    const int N = (by < 8) ? 512 : 256;
    const int bn = (by < 8) ? by * 64 : (by - 8) * 64;
    const int lane = threadIdx.x & 63, w = threadIdx.x >> 6;
    const int wm = (w >> 1) * 32, wn = (w & 1) * 32;
    const int lr = lane & 15, lq = lane >> 4;
    #pragma unroll
    for (int m = 0; m < 2; m++) {
        #pragma unroll
        for (int r = 0; r < 4; r++) {
            int row = bm + wm + m * 16 + lq * 4 + r;
            #pragma unroll
            for (int n = 0; n < 2; n++) {
                int col = bn + wn + n * 16 + lr;
                Yb[(size_t)row * N + col] = f2bf(acc[m][n][r]);
            }
        }
    }
}

// ---------------------------------------------------------------------------
// Fused FFN v2 (round-15 verified best, 56 us): R += relu(X @ W1^T) @ W2^T.
// Block = 64 tokens; hidden in 8 chunks of 64. W1c/W2c staged via batched
// global_load_lds into shared 32KB Wc; Hs 8KB. gemm1 swapped-operand ->
// packed 8B Hs stores. LDS 40KB -> 4 blocks/CU.
__global__ __launch_bounds__(256) void ffn_fused(const unsigned short* __restrict__ X,
                                                 const unsigned short* __restrict__ W1,
                                                 const unsigned short* __restrict__ W2,
                                                 unsigned short* __restrict__ R) {
    __shared__ unsigned short Wc[64 * 256];   // 32 KB (W1c [64][256] or W2c [256][64])
    __shared__ unsigned short Hs[64 * 64];    // 8 KB, row 128B, slot ^= row&7
    const int tid = threadIdx.x;
    const int lane = tid & 63, w = tid >> 6;
    const int lr = lane & 15, lq = lane >> 4;
    const int thm = (w >> 1) * 32;            // token rows for gemm2 A
    const int thb = (w & 1) * 32;             // token rows for gemm1 B (xf)
    const int hh  = (w >> 1) * 32;            // hidden rows for gemm1 A
    const int wn2 = (w & 1) * 128;            // out cols (gemm2)
    const int bm = blockIdx.x * 64;

    // X fragments (gemm1 B-operand): rows = tokens thb + nt*16 + lr
    bf16x8 xf[2][8];
    #pragma unroll
    for (int nt = 0; nt < 2; nt++) {
        const unsigned short* xr = X + (size_t)(bm + thb + nt * 16 + lr) * 256 + lq * 8;
        #pragma unroll
        for (int ks = 0; ks < 8; ks++)
            xf[nt][ks] = *(const bf16x8*)(xr + ks * 32);
    }

    f32x4 acc_o[2][8];
    #pragma unroll
    for (int m = 0; m < 2; m++)
        #pragma unroll
        for (int nt = 0; nt < 8; nt++)
            acc_o[m][nt] = (f32x4){0.f, 0.f, 0.f, 0.f};

    for (int hk = 0; hk < 8; hk++) {
        if (hk) __syncthreads();              // prev gemm2 LDS reads done
        // stage W1c: rows hk*64+h (h 0..63), 512B rows, 32 slots, slot^=(h&7)
        #pragma unroll
        for (int i = 0; i < 8; i++) {
            int d = (w << 13) + (i << 10) + (lane << 4);
            int h = d >> 9, s = (d >> 4) & 31;
            int ss = s ^ (h & 7);
            gload_lds16(W1 + (size_t)(hk * 64 + h) * 256 + ss * 8,
                        (char*)Wc + (w << 13) + (i << 10));
        }
        __syncthreads();                      // W1c ready (drains vmcnt)

        // gemm1 (swapped): acc1[mh][nt], D row = hidden, D col = token
        f32x4 acc1[2][2];
        #pragma unroll
        for (int mh = 0; mh < 2; mh++)
            #pragma unroll
            for (int nt = 0; nt < 2; nt++)
                acc1[mh][nt] = (f32x4){0.f, 0.f, 0.f, 0.f};
        #pragma unroll
        for (int ks = 0; ks < 8; ks++) {
            bf16x8 w1f[2];
            #pragma unroll
            for (int mh = 0; mh < 2; mh++) {
                int hrow = hh + mh * 16 + lr;
                int slot = ks * 4 + lq;
                w1f[mh] = *(const bf16x8*)((const char*)Wc + hrow * 512 + ((slot ^ (hrow & 7)) << 4));
            }
            #pragma unroll
            for (int mh = 0; mh < 2; mh++)
                #pragma unroll
                for (int nt = 0; nt < 2; nt++)
                    acc1[mh][nt] = __builtin_amdgcn_mfma_f32_16x16x32_bf16(w1f[mh], xf[nt][ks], acc1[mh][nt], 0, 0, 0);
        }
        // relu -> bf16 -> Hs[tok][hid], packed 8B per (mh,nt)
        #pragma unroll
        for (int mh = 0; mh < 2; mh++)
            #pragma unroll
            for (int nt = 0; nt < 2; nt++) {
                int hid0 = hh + mh * 16 + lq * 4;
                int tokr = thb + nt * 16 + lr;
                ushort4 pk;
                pk.x = f2bf(fmaxf(acc1[mh][nt][0], 0.0f));
                pk.y = f2bf(fmaxf(acc1[mh][nt][1], 0.0f));
                pk.z = f2bf(fmaxf(acc1[mh][nt][2], 0.0f));
                pk.w = f2bf(fmaxf(acc1[mh][nt][3], 0.0f));
                *(ushort4*)((char*)Hs + tokr * 128 +
                            (((hid0 >> 3) ^ (tokr & 7)) << 4) + (hid0 & 7) * 2) = pk;
            }
        __syncthreads();                      // Hs visible; W1c reads done

        // stage W2c: [256 out][64 k], 128B rows, 8 slots, slot^=(o&7)
        #pragma unroll
        for (int i = 0; i < 8; i++) {
            int d = (w << 13) + (i << 10) + (lane << 4);
            int o = d >> 7, s = (d >> 4) & 7;
            int ss = s ^ (o & 7);
            gload_lds16(W2 + (size_t)o * 512 + hk * 64 + ss * 8,
                        (char*)Wc + (w << 13) + (i << 10));
        }
        __syncthreads();                      // W2c ready

        // gemm2: out[64][256] += Hs[64][64] @ W2c^T, k=64
        #pragma unroll
        for (int ks = 0; ks < 2; ks++) {
            int slot = ks * 4 + lq;
            bf16x8 af2[2];
            #pragma unroll
            for (int m = 0; m < 2; m++) {
                int trow = thm + m * 16 + lr;
                af2[m] = *(const bf16x8*)((const char*)Hs + trow * 128 + ((slot ^ (trow & 7)) << 4));
            }
            #pragma unroll
            for (int nt = 0; nt < 8; nt++) {
                int orow = wn2 + nt * 16 + lr;
                bf16x8 b2 = *(const bf16x8*)((const char*)Wc + orow * 128 + ((slot ^ (orow & 7)) << 4));
                #pragma unroll
                for (int m = 0; m < 2; m++)
                    acc_o[m][nt] = __builtin_amdgcn_mfma_f32_16x16x32_bf16(af2[m], b2, acc_o[m][nt], 0, 0, 0);
            }
        }
    }
    // epilogue: in-place residual add on R
    #pragma unroll
    for (int m = 0; m < 2; m++)
        #pragma unroll
        for (int nt = 0; nt < 8; nt++)
            #pragma unroll
            for (int r = 0; r < 4; r++) {
                int row = bm + thm + m * 16 + lq * 4 + r;
                int col = wn2 + nt * 16 + lr;
                size_t off = (size_t)row * 256 + col;
                R[off] = f2bf(acc_o[m][nt][r] + bf2f(R[off]));
            }
}

// ---------------------------------------------------------------------------
// V transpose: Vtok[t][256] bf16 -> Vt[h][col][d(32)][l(160)] bf16
__global__ __launch_bounds__(256) void vtrans(const unsigned short* __restrict__ vtok,
                                              unsigned short* __restrict__ vt, int W) {
    const int col = blockIdx.x, h = blockIdx.y;
    __shared__ unsigned short t[160][34];
    const int tid = threadIdx.x;
    for (int i = tid; i < 160 * 16; i += 256) {
        int l = i >> 4, dp = i & 15;
        unsigned v = *(const unsigned*)(vtok + ((size_t)l * W + col) * 256 + h * 32 + dp * 2);
        *(unsigned*)&t[l][dp * 2] = v;
    }
    __syncthreads();
    unsigned short* dst = vt + (((size_t)h * W + col) * 32) * 160;
    for (int i = tid; i < 32 * 160; i += 256) {
        int d = i / 160, l = i - d * 160;
        dst[i] = t[l][d];
    }
}

// ---------------------------------------------------------------------------
// MFMA attention (verified round 4/5), bf16 in/out
__global__ __launch_bounds__(64) void attn_mfma(const unsigned short* __restrict__ qk,
                                                const unsigned short* __restrict__ vt,
                                                unsigned short* __restrict__ o, int W) {
    const int col = blockIdx.x;
    const int h = blockIdx.y;
    const int lane = threadIdx.x;
    const int lr = lane & 15, lq = lane >> 4;
    __shared__ __align__(16) unsigned short P_lds[16][168];

    bf16x8 kf[10];
    #pragma unroll
    for (int m = 0; m < 10; m++) {
        size_t t = (size_t)(m * 16 + lr) * W + col;
        kf[m] = *(const bf16x8*)(qk + t * 512 + 256 + h * 32 + lq * 8);
    }
    const unsigned short* vbase = vt + (((size_t)h * W + col) * 32) * 160;
    bf16x8 vf[2][5];
    #pragma unroll
    for (int md = 0; md < 2; md++)
        #pragma unroll
        for (int c = 0; c < 5; c++)
            vf[md][c] = *(const bf16x8*)(vbase + (size_t)(md * 16 + lr) * 160 + c * 32 + lq * 8);

    const float scale = 0.17677669529663687f;
    for (int n = 0; n < 10; n++) {
        const int q = n * 16 + lr;
        bf16x8 qf = *(const bf16x8*)(qk + ((size_t)q * W + col) * 512 + h * 32 + lq * 8);
        f32x4 p[10];
        #pragma unroll
        for (int m = 0; m < 10; m++)
            p[m] = __builtin_amdgcn_mfma_f32_16x16x32_bf16(kf[m], qf, (f32x4){0.f,0.f,0.f,0.f}, 0, 0, 0);
        const int b = lq * 4 - ((n & 1) * 16 + lr);
        float mx = -1e30f;
        #pragma unroll
        for (int m = 0; m < 10; m++) {
            #pragma unroll
            for (int r = 0; r < 4; r++) {
                int dd = b + (m & 1) * 16 + r;
                float s = ((unsigned)(dd + 5) <= 10u) ? p[m][r] : -1e30f;
                p[m][r] = s;
                mx = fmaxf(mx, s);
            }
        }
        mx = fmaxf(mx, __shfl_xor(mx, 16));
        mx = fmaxf(mx, __shfl_xor(mx, 32));
        float sum = 0.f;
        #pragma unroll
        for (int m = 0; m < 10; m++) {
            #pragma unroll
            for (int r = 0; r < 4; r++) {
                float e = __expf((p[m][r] - mx) * scale);
                p[m][r] = e;
                sum += e;
            }
        }
        sum += __shfl_xor(sum, 16);
        sum += __shfl_xor(sum, 32);
        #pragma unroll
        for (int m = 0; m < 10; m++) {
            ushort4 pk;
            pk.x = f2bf(p[m][0]); pk.y = f2bf(p[m][1]);
            pk.z = f2bf(p[m][2]); pk.w = f2bf(p[m][3]);
            *(ushort4*)&P_lds[lr][m * 16 + lq * 4] = pk;
        }
        f32x4 oa0 = (f32x4){0.f,0.f,0.f,0.f}, oa1 = (f32x4){0.f,0.f,0.f,0.f};
        #pragma unroll
        for (int c = 0; c < 5; c++) {
            bf16x8 pf = *(const bf16x8*)&P_lds[lr][c * 32 + lq * 8];
            oa0 = __builtin_amdgcn_mfma_f32_16x16x32_bf16(vf[0][c], pf, oa0, 0, 0, 0);
            oa1 = __builtin_amdgcn_mfma_f32_16x16x32_bf16(vf[1][c], pf, oa1, 0, 0, 0);
        }
        const float inv = 1.0f / sum;
        unsigned short* op = o + ((size_t)q * W + col) * 256 + h * 32;
        ushort4 s0, s1;
        s0.x = f2bf(oa0[0] * inv); s0.y = f2bf(oa0[1] * inv);
        s0.z = f2bf(oa0[2] * inv); s0.w = f2bf(oa0[3] * inv);
        s1.x = f2bf(oa1[0] * inv); s1.y = f2bf(oa1[1] * inv);
        s1.z = f2bf(oa1[2] * inv); s1.w = f2bf(oa1[3] * inv);
        *(ushort4*)(op + lq * 4)      = s0;
        *(ushort4*)(op + 16 + lq * 4) = s1;
    }
}

// ---------------------------------------------------------------------------
// conv as implicit MFMA GEMM (verified round 3)
__global__ __launch_bounds__(256) void conv_mfma(const unsigned short* __restrict__ xp,
                                                 const unsigned short* __restrict__ wb,
                                                 const float* __restrict__ res,
                                                 float* __restrict__ out, int bb0) {
    const int ptile = blockIdx.x;
    const int slice = blockIdx.y;
    const int lb = slice / 25, n = slice % 25;
    const int bb = bb0 + lb;
    const int y0 = ptile * 4;
    __shared__ unsigned short As[128 * 64];
    __shared__ unsigned short Bs[128 * 64];
    const int tid = threadIdx.x;
    const int lane = tid & 63, w = tid >> 6;
    const int wm = (w >> 1) * 64;
    const int wn = (w & 1) * 64;
    const int lr = lane & 15, lq = lane >> 4;
    const unsigned short* xs = xp + (size_t)slice * 1024 * 128;
    f32x4 acc[4][4];
    #pragma unroll
    for (int m = 0; m < 4; m++)
        #pragma unroll
        for (int nn = 0; nn < 4; nn++)
            acc[m][nn] = (f32x4){0.f, 0.f, 0.f, 0.f};

    for (int tap = 0; tap < 9; tap++) {
        const int dy = tap / 3 - 1, dx = tap % 3 - 1;
        for (int c0 = 0; c0 < 128; c0 += 64) {
            #pragma unroll
            for (int i = 0; i < 4; i++) {
                int id = tid + 256 * i;
                int row = id >> 3, cg = id & 7;
                int py = y0 + (row >> 5) + dy;
                int px = (row & 31) + dx;
                uint4 v = {0u, 0u, 0u, 0u};
                if ((unsigned)py < 32u && (unsigned)px < 32u)
                    v = *(const uint4*)(xs + ((size_t)(py * 32 + px) * 128 + c0 + cg * 8));
                int boff = row * 128 + ((cg * 16) ^ ((row & 7) << 4));
                *(uint4*)((char*)As + boff) = v;
            }
            #pragma unroll
            for (int i = 0; i < 4; i++) {
                int id = tid + 256 * i;
                int row = id >> 3, cg = id & 7;
                uint4 v = *(const uint4*)(wb + (((size_t)tap * 128 + row) * 128 + c0 + cg * 8));
                int boff = row * 128 + ((cg * 16) ^ ((row & 7) << 4));
                *(uint4*)((char*)Bs + boff) = v;
            }
            __syncthreads();
            #pragma unroll
            for (int ks = 0; ks < 2; ks++) {
                bf16x8 wf[4], xf[4];
                #pragma unroll
                for (int m = 0; m < 4; m++) {
                    int row = wm + m * 16 + lr;
                    int boff = row * 128 + ((ks * 64 + lq * 16) ^ ((row & 7) << 4));
                    wf[m] = *(const bf16x8*)((const char*)Bs + boff);
                }
                #pragma unroll
                for (int nn = 0; nn < 4; nn++) {
                    int row = wn + nn * 16 + lr;
                    int boff = row * 128 + ((ks * 64 + lq * 16) ^ ((row & 7) << 4));
                    xf[nn] = *(const bf16x8*)((const char*)As + boff);
                }
                #pragma unroll
                for (int m = 0; m < 4; m++)
                    #pragma unroll
                    for (int nn = 0; nn < 4; nn++)
                        acc[m][nn] = __builtin_amdgcn_mfma_f32_16x16x32_bf16(wf[m], xf[nn], acc[m][nn], 0, 0, 0);
            }
            __syncthreads();
        }
    }
    #pragma unroll
    for (int m = 0; m < 4; m++) {
        int co0 = wm + m * 16 + lq * 4;
        #pragma unroll
        for (int r = 0; r < 4; r++) {
            size_t rowoff = (((size_t)(bb * 128 + co0 + r) * 25 + n) * 1024) + ptile * 128;
            #pragma unroll
            for (int nn = 0; nn < 4; nn++) {
                int pix = wn + nn * 16 + lr;
                out[rowoff + pix] = acc[m][nn][r] + res[rowoff + pix];
            }
        }
    }
}

// ---------------------------------------------------------------------------
extern "C" void kernel_launch(void* const* d_in, const int* in_sizes, int n_in,
                              void* d_out, int out_size, void* d_ws, size_t ws_size,
                              hipStream_t stream) {
    (void)in_sizes; (void)n_in; (void)out_size;
    const float* buffer     = (const float*)d_in[0];
    const float* Win        = (const float*)d_in[1];
    const float* ln_w       = (const float*)d_in[2];
    const float* ln_b       = (const float*)d_in[3];
    const float* in_proj    = (const float*)d_in[4];
    const float* attn_out_w = (const float*)d_in[5];
    const float* ffn_ln_w   = (const float*)d_in[6];
    const float* ffn_ln_b   = (const float*)d_in[7];
    const float* ff1        = (const float*)d_in[8];
    const float* ff2        = (const float*)d_in[9];
    const float* Wout       = (const float*)d_in[10];
    const float* conv_w     = (const float*)d_in[11];
    float* out = (float*)d_out;
    float* ws  = (float*)d_ws;

    const size_t need2 = ((size_t)51200 * 960 + 368640) * 4;
    int NBB = (ws_size >= need2) ? 2 : 1;
    const int W = NBB * 160;
    const size_t T = (size_t)NBB * 25600;

    // layout (float-slot offsets); all bf16
    unsigned short* x0b   = (unsigned short*)ws;                 // T*128 bf16
    unsigned short* Abf   = (unsigned short*)(ws + T * 64);      // T*256 bf16 residual
    unsigned short* tnb   = (unsigned short*)(ws + T * 192);     // T*256 bf16
    float*          C     = ws + T * 320;                        // T*512 fl region
    unsigned short* QKtok = (unsigned short*)C;                  // T*512 bf16
    unsigned short* Vtok  = (unsigned short*)(C + T * 256);      // T*256 bf16
    unsigned short* Vt    = (unsigned short*)(C + T * 384);      // T*256 bf16
    unsigned short* xp    = (unsigned short*)C;                  // T*128 bf16
    unsigned short* Db    = (unsigned short*)(ws + T * 832);     // T*256 bf16
    unsigned short* wg    = (unsigned short*)(ws + T * 960);     // 589824 bf16
    unsigned short* wb    = (unsigned short*)(ws + T * 960 + 294912); // 147456 bf16

    const unsigned short* Winb  = wg;
    const unsigned short* Wqkvb = wg + 32768;            // 768 rows: [Wq;Wk;Wv]
    const unsigned short* Waob  = wg + 229376;
    const unsigned short* Wff1b = wg + 294912;
    const unsigned short* Wff2b = wg + 425984;
    const unsigned short* Woutb = wg + 557056;

    const int GM64 = (int)(T / 64);      // 800 (or 400), % 8 == 0

    conv_weights<<<2304, 256, 0, stream>>>(Win, in_proj, attn_out_w, ff1, ff2, Wout, wg);
    repack_w<<<576, 256, 0, stream>>>(conv_w, wb);

    for (int pass = 0; pass < 2; pass++) {
        const float* src = (pass == 0) ? buffer : out;
        for (int bb0 = 0; bb0 < 2; bb0 += NBB) {
            if (pass == 0) gather1<<<dim3(128, 25, NBB), 256, 0, stream>>>(src, x0b, W, bb0);
            else           gather2<<<dim3(128, 25, NBB), 256, 0, stream>>>(src, x0b, W, bb0);

            // tok = x0 @ Win^T (K=128) -> Abf
            gemm_bf16<<<dim3(GM64, 4), 256, 0, stream>>>(x0b, Winb, Abf, nullptr, 256, 128, 0, 0, W);
            ln_bf16<<<(int)(T / 4), 256, 0, stream>>>(Abf, tnb, ln_w, ln_b);
            // fused qk (tn) + v (tok) projections, K=256
            gemm_qkv<<<dim3(GM64, 12), 256, 0, stream>>>(tnb, Abf, Wqkvb, QKtok, Vtok);
            vtrans<<<dim3(W, 8), 256, 0, stream>>>(Vtok, Vt, W);
            attn_mfma<<<dim3(W, 8), 64, 0, stream>>>(QKtok, Vt, Db, W);
            // tok += ob @ attn_out_w^T  (in-place bf16 residual)
            gemm_bf16<<<dim3(GM64, 4), 256, 0, stream>>>(Db, Waob, Abf, Abf, 256, 256, 0, 0, W);
            ln_bf16<<<(int)(T / 4), 256, 0, stream>>>(Abf, tnb, ffn_ln_w, ffn_ln_b);
            // fused FFN: Abf += relu(tnb @ ff1^T) @ ff2^T
            ffn_fused<<<GM64, 256, 0, stream>>>(tnb, Wff1b, Wff2b, Abf);
            // ot = tok @ Wout^T (N=128) -> fused scatter into xp (pixel-major)
            gemm_bf16<<<dim3(GM64, 2), 256, 0, stream>>>(Abf, Woutb, xp, nullptr, 128, 256, 0, pass + 1, W);

            conv_mfma<<<dim3(8, NBB * 25), 256, 0, stream>>>(
                xp, wb, (pass == 0) ? buffer : (const float*)out, out, bb0);
        }
    }
}

// Round 19
// 557.054 us; speedup vs baseline: 1.2954x; 1.0045x over previous
//
#include <hip/hip_runtime.h>
#include <math.h>
#include <stdint.h>

typedef __attribute__((ext_vector_type(8))) short bf16x8;
typedef __attribute__((ext_vector_type(4))) float f32x4;

static __device__ __forceinline__ unsigned short f2bf(float f) {
    unsigned u = __builtin_bit_cast(unsigned, f);
    unsigned r = u + 0x7fffu + ((u >> 16) & 1u);   // RNE
    return (unsigned short)(r >> 16);
}
static __device__ __forceinline__ float bf2f(unsigned short h) {
    return __builtin_bit_cast(float, ((unsigned)h) << 16);
}
// async global->LDS, 16B per lane; lds dest = uniform base + lane*16
static __device__ __forceinline__ void gload_lds16(const void* g, void* l) {
    __builtin_amdgcn_global_load_lds((const __attribute__((address_space(1))) unsigned int*)g,
                                     (__attribute__((address_space(3))) unsigned int*)l, 16, 0, 0);
}

// ---------------------------------------------------------------------------
// gather pass1: x0b[t'][cc] (bf16) = src[bb][cc][u*5+v][y][x]
__global__ __launch_bounds__(256) void gather1(const float* __restrict__ src,
                                               unsigned short* __restrict__ x0, int W, int bb0) {
    int cct = blockIdx.x & 3, y = blockIdx.x >> 2;
    int n = blockIdx.y; int u = n / 5, v = n % 5;
    int lb = blockIdx.z, bb = bb0 + lb;
    __shared__ float tile[32][33];
    int tx = threadIdx.x & 31, tg = threadIdx.x >> 5;
    const float* s = src + (((size_t)(bb * 128 + cct * 32) * 25 + n) * 32 + y) * 32;
    #pragma unroll
    for (int i = 0; i < 4; i++) {
        int cl = tg + 8 * i;
        tile[cl][tx] = s[(size_t)cl * 25600 + tx];
    }
    __syncthreads();
    unsigned short* d = x0 + ((size_t)(u * 32 + y) * W + lb * 160 + v * 32) * 128 + cct * 32;
    #pragma unroll
    for (int i = 0; i < 4; i++) {
        int xx = tg + 8 * i;
        d[(size_t)xx * 128 + tx] = f2bf(tile[tx][xx]);
    }
}

// gather pass2
__global__ __launch_bounds__(256) void gather2(const float* __restrict__ src,
                                               unsigned short* __restrict__ x0, int W, int bb0) {
    int cct = blockIdx.x & 3, x = blockIdx.x >> 2;
    int n = blockIdx.y; int u = n / 5, v = n % 5;
    int lb = blockIdx.z, bb = bb0 + lb;
    __shared__ float tile[32][33];
    int tx = threadIdx.x & 31, tg = threadIdx.x >> 5;
    const float* s = src + (((size_t)(bb * 128 + cct * 32) * 25 + n) * 32) * 32 + x;
    #pragma unroll
    for (int i = 0; i < 4; i++) {
        int cl = tg + 8 * i;
        tile[cl][tx] = s[(size_t)cl * 25600 + tx * 32];
    }
    __syncthreads();
    unsigned short* d = x0 + ((size_t)(v * 32 + x) * W + lb * 160 + u * 32) * 128 + cct * 32;
    #pragma unroll
    for (int i = 0; i < 4; i++) {
        int yy = tg + 8 * i;
        d[(size_t)yy * 128 + tx] = f2bf(tile[tx][yy]);
    }
}

// ---------------------------------------------------------------------------
// conv weight repack: conv_w[co][ci][tap(9)] f32 -> wb[tap][co][ci] bf16
__global__ __launch_bounds__(256) void repack_w(const float* __restrict__ cw,
                                                unsigned short* __restrict__ wb) {
    int g = blockIdx.x * 256 + threadIdx.x;
    int co = g / 1152;
    int rem = g - co * 1152;
    int ci = rem / 9, tap = rem - ci * 9;
    wb[((size_t)tap * 128 + co) * 128 + ci] = f2bf(cw[g]);
}

// GEMM weights -> one bf16 buffer (layout preserved [N][K])
__global__ __launch_bounds__(256) void conv_weights(const float* __restrict__ Win,
                                                    const float* __restrict__ in_proj,
                                                    const float* __restrict__ attn_out_w,
                                                    const float* __restrict__ ff1,
                                                    const float* __restrict__ ff2,
                                                    const float* __restrict__ Wout,
                                                    unsigned short* __restrict__ wg) {
    int g = blockIdx.x * 256 + threadIdx.x;      // 589824 total
    float v;
    if      (g < 32768)  v = Win[g];
    else if (g < 229376) v = in_proj[g - 32768];
    else if (g < 294912) v = attn_out_w[g - 229376];
    else if (g < 425984) v = ff1[g - 294912];
    else if (g < 557056) v = ff2[g - 425984];
    else                 v = Wout[g - 557056];
    wg[g] = f2bf(v);
}

// ---------------------------------------------------------------------------
// XCD/L2-aware block remap (requires gridDim.x % 8 == 0)
static __device__ __forceinline__ void xcd_remap(int& bxi, int& byi) {
    int d = blockIdx.x + gridDim.x * blockIdx.y;
    int s = d & 7;
    unsigned j = (unsigned)(d >> 3);
    unsigned ny = gridDim.y;
    int gm8 = (int)(gridDim.x >> 3);
    bxi = s * gm8 + (int)(j / ny);
    byi = (int)(j % ny);
}

// ---------------------------------------------------------------------------
// GEMM core 64x64: BK=32, 2-buffer global_load_lds pipeline (round-12 best).
// LDS 16KB -> ~8 blocks/CU. 16B-slot swizzle slot ^= (row>>1)&3.
static __device__ __forceinline__ void gemm_core64(const unsigned short* __restrict__ X,
                                                   const unsigned short* __restrict__ Wt,
                                                   int bm, int bnrow, int K,
                                                   unsigned short (&As)[2][64 * 32],
                                                   unsigned short (&Bs)[2][64 * 32],
                                                   f32x4 (&acc)[2][2]) {
    const int tid = threadIdx.x;
    const int lane = tid & 63, w = tid >> 6;
    const int wm = (w >> 1) * 32, wn = (w & 1) * 32;
    const int lr = lane & 15, lq = lane >> 4;
    #pragma unroll
    for (int m = 0; m < 2; m++)
        #pragma unroll
        for (int n = 0; n < 2; n++)
            acc[m][n] = (f32x4){0.f, 0.f, 0.f, 0.f};

    const int srow = tid >> 2, sslot = tid & 3;
    const int ssl = sslot ^ ((srow >> 1) & 3);
    auto STAGE = [&](int bsel, int k0) {
        gload_lds16(X  + (size_t)(bm + srow) * K + k0 + ssl * 8,
                    &As[bsel][tid * 8]);
        gload_lds16(Wt + (size_t)(bnrow + srow) * K + k0 + ssl * 8,
                    &Bs[bsel][tid * 8]);
    };

    const int nt = K >> 5;
    STAGE(0, 0);
    __syncthreads();
    int cur = 0;
    for (int t = 0; t < nt; ++t) {
        if (t + 1 < nt) STAGE(cur ^ 1, (t + 1) << 5);
        const char* Ab = (const char*)As[cur];
        const char* Bb = (const char*)Bs[cur];
        bf16x8 af[2], bf[2];
        #pragma unroll
        for (int m = 0; m < 2; m++) {
            int row = wm + m * 16 + lr;
            af[m] = *(const bf16x8*)(Ab + row * 64 + ((lq * 16) ^ (((row >> 1) & 3) << 4)));
        }
        #pragma unroll
        for (int n = 0; n < 2; n++) {
            int row = wn + n * 16 + lr;
            bf[n] = *(const bf16x8*)(Bb + row * 64 + ((lq * 16) ^ (((row >> 1) & 3) << 4)));
        }
        #pragma unroll
        for (int m = 0; m < 2; m++)
            #pragma unroll
            for (int n = 0; n < 2; n++)
                acc[m][n] = __builtin_amdgcn_mfma_f32_16x16x32_bf16(af[m], bf[n], acc[m][n], 0, 0, 0);
        if (t + 1 < nt) __syncthreads();
        cur ^= 1;
    }
}

// general GEMM: Y = X @ Wt^T (+Rb) (relu?), spass=1/2 fused scatter epilogue
__global__ __launch_bounds__(256) void gemm_bf16(const unsigned short* __restrict__ X,
                                                 const unsigned short* __restrict__ Wt,
                                                 unsigned short* __restrict__ Yb,
                                                 const unsigned short* __restrict__ Rb,
                                                 int N, int K, int relu, int spass, int W) {
    __shared__ unsigned short As[2][64 * 32];
    __shared__ unsigned short Bs[2][64 * 32];
    int bxi, byi;
    xcd_remap(bxi, byi);
    const int bm = bxi * 64, bn = byi * 64;
    f32x4 acc[2][2];
    gemm_core64(X, Wt, bm, bn, K, As, Bs, acc);

    const int lane = threadIdx.x & 63, w = threadIdx.x >> 6;
    const int wm = (w >> 1) * 32, wn = (w & 1) * 32;
    const int lr = lane & 15, lq = lane >> 4;
    #pragma unroll
    for (int m = 0; m < 2; m++) {
        #pragma unroll
        for (int r = 0; r < 4; r++) {
            int row = bm + wm + m * 16 + lq * 4 + r;
            size_t base;
            if (spass == 0) {
                base = (size_t)row * N;
            } else {
                int l = row / W, c = row - l * W;
                int lb = (c >= 160) ? 1 : 0, sp = c - lb * 160;
                int sl_, pix;
                if (spass == 1) { int u = l >> 5, y = l & 31, v = sp >> 5, x = sp & 31;
                                  sl_ = lb * 25 + u * 5 + v; pix = y * 32 + x; }
                else            { int v = l >> 5, x = l & 31, u = sp >> 5, y = sp & 31;
                                  sl_ = lb * 25 + u * 5 + v; pix = y * 32 + x; }
                base = ((size_t)sl_ * 1024 + pix) * 128;
            }
            #pragma unroll
            for (int n = 0; n < 2; n++) {
                int col = bn + wn + n * 16 + lr;
                float val = acc[m][n][r];
                if (Rb) val += bf2f(Rb[(size_t)row * N + col]);
                if (relu) val = fmaxf(val, 0.0f);
                Yb[base + col] = f2bf(val);
            }
        }
    }
}

// fused qk+v GEMM (64x64 tiles): in_proj rows [0..767] = [Wq;Wk;Wv], K=256.
__global__ __launch_bounds__(256) void gemm_qkv(const unsigned short* __restrict__ tn,
                                                const unsigned short* __restrict__ tok,
                                                const unsigned short* __restrict__ Wqkv,
                                                unsigned short* __restrict__ QK,
                                                unsigned short* __restrict__ V) {
    __shared__ unsigned short As[2][64 * 32];
    __shared__ unsigned short Bs[2][64 * 32];
    int bxi, by;
    xcd_remap(bxi, by);
    const int bm = bxi * 64;
    const unsigned short* X = (by < 8) ? tn : tok;
    f32x4 acc[2][2];
    gemm_core64(X, Wqkv, bm, by * 64, 256, As, Bs, acc);

    unsigned short* Yb = (by < 8) ? QK : V;
    const int N = (by < 8) ? 512 : 256;
    const int bn = (by < 8) ? by * 64 : (by - 8) * 64;
    const int lane = threadIdx.x & 63, w = threadIdx.x >> 6;
    const int wm = (w >> 1) * 32, wn = (w & 1) * 32;
    const int lr = lane & 15, lq = lane >> 4;
    #pragma unroll
    for (int m = 0; m < 2; m++) {
        #pragma unroll
        for (int r = 0; r < 4; r++) {
            int row = bm + wm + m * 16 + lq * 4 + r;
            #pragma unroll
            for (int n = 0; n < 2; n++) {
                int col = bn + wn + n * 16 + lr;
                Yb[(size_t)row * N + col] = f2bf(acc[m][n][r]);
            }
        }
    }
}

// ---------------------------------------------------------------------------
// Full-row GEMM (64 tok x 256 cols) with FUSED LayerNorm epilogue.
// Yraw = bf16(X@Wt^T (+Rb));  Tn = bf16(LN_f32(X@Wt^T (+Rb)) * lnw + lnb).
// LN stats computed on f32 pre-rounding values (closer to reference).
// Per-row reduce: 8-val thread partial -> shfl_xor over lr-group -> 1KB LDS
// exchange across the 2 col-half waves. LDS 41KB -> 3 blocks/CU.
// In-place Rb==Yraw safe: each (row,col) read+written by exactly one thread.
__global__ __launch_bounds__(256) void gemm_ln(const unsigned short* __restrict__ X,
                                               const unsigned short* __restrict__ Wt,
                                               const unsigned short* __restrict__ Rb,
                                               unsigned short* __restrict__ Yraw,
                                               unsigned short* __restrict__ Tn,
                                               const float* __restrict__ lnw,
                                               const float* __restrict__ lnb, int K) {
    __shared__ unsigned short As[2][64 * 32];     // 4KB each
    __shared__ unsigned short Bs[2][256 * 32];    // 16KB each
    __shared__ float red_s[64][2], red_q[64][2];  // 1KB
    const int tid = threadIdx.x;
    const int lane = tid & 63, w = tid >> 6;
    const int lr = lane & 15, lq = lane >> 4;
    const int thm = (w >> 1) * 32;                // token rows
    const int wn2 = (w & 1) * 128;                // col half
    const int bm = blockIdx.x * 64;

    f32x4 acc[2][8];
    #pragma unroll
    for (int m = 0; m < 2; m++)
        #pragma unroll
        for (int n = 0; n < 8; n++)
            acc[m][n] = (f32x4){0.f, 0.f, 0.f, 0.f};

    const int srow = tid >> 2, sslot = tid & 3;
    auto STAGE = [&](int bsel, int k0) {
        {   int ssl = sslot ^ ((srow >> 1) & 3);
            gload_lds16(X + (size_t)(bm + srow) * K + k0 + ssl * 8, &As[bsel][tid * 8]); }
        #pragma unroll
        for (int i = 0; i < 4; i++) {
            int row = i * 64 + srow;
            int ssl = sslot ^ ((row >> 1) & 3);
            gload_lds16(Wt + (size_t)row * K + k0 + ssl * 8, &Bs[bsel][(i * 256 + tid) * 8]);
        }
    };

    const int ntk = K >> 5;
    STAGE(0, 0);
    __syncthreads();
    int cur = 0;
    for (int t = 0; t < ntk; ++t) {
        if (t + 1 < ntk) STAGE(cur ^ 1, (t + 1) << 5);
        const char* Ab = (const char*)As[cur];
        const char* Bb = (const char*)Bs[cur];
        bf16x8 af[2], bf[8];
        #pragma unroll
        for (int m = 0; m < 2; m++) {
            int row = thm + m * 16 + lr;
            af[m] = *(const bf16x8*)(Ab + row * 64 + ((lq * 16) ^ (((row >> 1) & 3) << 4)));
        }
        #pragma unroll
        for (int n = 0; n < 8; n++) {
            int row = wn2 + n * 16 + lr;
            bf[n] = *(const bf16x8*)(Bb + row * 64 + ((lq * 16) ^ (((row >> 1) & 3) << 4)));
        }
        #pragma unroll
        for (int m = 0; m < 2; m++)
            #pragma unroll
            for (int n = 0; n < 8; n++)
                acc[m][n] = __builtin_amdgcn_mfma_f32_16x16x32_bf16(af[m], bf[n], acc[m][n], 0, 0, 0);
        if (t + 1 < ntk) __syncthreads();
        cur ^= 1;
    }

    // residual add (f32) -- all reads complete before any Yraw write below
    if (Rb) {
        #pragma unroll
        for (int m = 0; m < 2; m++)
            #pragma unroll
            for (int n = 0; n < 8; n++)
                #pragma unroll
                for (int r = 0; r < 4; r++) {
                    int row = bm + thm + m * 16 + lq * 4 + r;
                    int col = wn2 + n * 16 + lr;
                    acc[m][n][r] += bf2f(Rb[(size_t)row * 256 + col]);
                }
    }
    // per-row partial sums -> shfl butterfly over lr -> LDS exchange
    #pragma unroll
    for (int m = 0; m < 2; m++)
        #pragma unroll
        for (int r = 0; r < 4; r++) {
            float s = 0.f, q = 0.f;
            #pragma unroll
            for (int n = 0; n < 8; n++) {
                float v = acc[m][n][r];
                s += v; q += v * v;
            }
            #pragma unroll
            for (int off = 1; off < 16; off <<= 1) {
                s += __shfl_xor(s, off);
                q += __shfl_xor(q, off);
            }
            if (lr == 0) {
                int rt = thm + m * 16 + lq * 4 + r;
                red_s[rt][w & 1] = s;
                red_q[rt][w & 1] = q;
            }
        }
    __syncthreads();
    float wv[8], bv[8];
    #pragma unroll
    for (int n = 0; n < 8; n++) {
        wv[n] = lnw[wn2 + n * 16 + lr];
        bv[n] = lnb[wn2 + n * 16 + lr];
    }
    #pragma unroll
    for (int m = 0; m < 2; m++)
        #pragma unroll
        for (int r = 0; r < 4; r++) {
            int rt = thm + m * 16 + lq * 4 + r;
            float s = red_s[rt][0] + red_s[rt][1];
            float q = red_q[rt][0] + red_q[rt][1];
            float mu = s * (1.0f / 256.0f);
            float inv = rsqrtf(q * (1.0f / 256.0f) - mu * mu + 1e-5f);
            int row = bm + rt;
            #pragma unroll
            for (int n = 0; n < 8; n++) {
                int col = wn2 + n * 16 + lr;
                float v = acc[m][n][r];
                size_t off = (size_t)row * 256 + col;
                Yraw[off] = f2bf(v);
                Tn[off]   = f2bf((v - mu) * inv * wv[n] + bv[n]);
            }
        }
}

// ---------------------------------------------------------------------------
// Fused FFN v2 (round-15 verified best): R += relu(X @ W1^T) @ W2^T.
__global__ __launch_bounds__(256) void ffn_fused(const unsigned short* __restrict__ X,
                                                 const unsigned short* __restrict__ W1,
                                                 const unsigned short* __restrict__ W2,
                                                 unsigned short* __restrict__ R) {
    __shared__ unsigned short Wc[64 * 256];   // 32 KB (W1c [64][256] or W2c [256][64])
    __shared__ unsigned short Hs[64 * 64];    // 8 KB, row 128B, slot ^= row&7
    const int tid = threadIdx.x;
    const int lane = tid & 63, w = tid >> 6;
    const int lr = lane & 15, lq = lane >> 4;
    const int thm = (w >> 1) * 32;            // token rows for gemm2 A
    const int thb = (w & 1) * 32;             // token rows for gemm1 B (xf)
    const int hh  = (w >> 1) * 32;            // hidden rows for gemm1 A
    const int wn2 = (w & 1) * 128;            // out cols (gemm2)
    const int bm = blockIdx.x * 64;

    bf16x8 xf[2][8];
    #pragma unroll
    for (int nt = 0; nt < 2; nt++) {
        const unsigned short* xr = X + (size_t)(bm + thb + nt * 16 + lr) * 256 + lq * 8;
        #pragma unroll
        for (int ks = 0; ks < 8; ks++)
            xf[nt][ks] = *(const bf16x8*)(xr + ks * 32);
    }

    f32x4 acc_o[2][8];
    #pragma unroll
    for (int m = 0; m < 2; m++)
        #pragma unroll
        for (int nt = 0; nt < 8; nt++)
            acc_o[m][nt] = (f32x4){0.f, 0.f, 0.f, 0.f};

    for (int hk = 0; hk < 8; hk++) {
        if (hk) __syncthreads();
        #pragma unroll
        for (int i = 0; i < 8; i++) {
            int d = (w << 13) + (i << 10) + (lane << 4);
            int h = d >> 9, s = (d >> 4) & 31;
            int ss = s ^ (h & 7);
            gload_lds16(W1 + (size_t)(hk * 64 + h) * 256 + ss * 8,
                        (char*)Wc + (w << 13) + (i << 10));
        }
        __syncthreads();

        f32x4 acc1[2][2];
        #pragma unroll
        for (int mh = 0; mh < 2; mh++)
            #pragma unroll
            for (int nt = 0; nt < 2; nt++)
                acc1[mh][nt] = (f32x4){0.f, 0.f, 0.f, 0.f};
        #pragma unroll
        for (int ks = 0; ks < 8; ks++) {
            bf16x8 w1f[2];
            #pragma unroll
            for (int mh = 0; mh < 2; mh++) {
                int hrow = hh + mh * 16 + lr;
                int slot = ks * 4 + lq;
                w1f[mh] = *(const bf16x8*)((const char*)Wc + hrow * 512 + ((slot ^ (hrow & 7)) << 4));
            }
            #pragma unroll
            for (int mh = 0; mh < 2; mh++)
                #pragma unroll
                for (int nt = 0; nt < 2; nt++)
                    acc1[mh][nt] = __builtin_amdgcn_mfma_f32_16x16x32_bf16(w1f[mh], xf[nt][ks], acc1[mh][nt], 0, 0, 0);
        }
        #pragma unroll
        for (int mh = 0; mh < 2; mh++)
            #pragma unroll
            for (int nt = 0; nt < 2; nt++) {
                int hid0 = hh + mh * 16 + lq * 4;
                int tokr = thb + nt * 16 + lr;
                ushort4 pk;
                pk.x = f2bf(fmaxf(acc1[mh][nt][0], 0.0f));
                pk.y = f2bf(fmaxf(acc1[mh][nt][1], 0.0f));
                pk.z = f2bf(fmaxf(acc1[mh][nt][2], 0.0f));
                pk.w = f2bf(fmaxf(acc1[mh][nt][3], 0.0f));
                *(ushort4*)((char*)Hs + tokr * 128 +
                            (((hid0 >> 3) ^ (tokr & 7)) << 4) + (hid0 & 7) * 2) = pk;
            }
        __syncthreads();

        #pragma unroll
        for (int i = 0; i < 8; i++) {
            int d = (w << 13) + (i << 10) + (lane << 4);
            int o = d >> 7, s = (d >> 4) & 7;
            int ss = s ^ (o & 7);
            gload_lds16(W2 + (size_t)o * 512 + hk * 64 + ss * 8,
                        (char*)Wc + (w << 13) + (i << 10));
        }
        __syncthreads();

        #pragma unroll
        for (int ks = 0; ks < 2; ks++) {
            int slot = ks * 4 + lq;
            bf16x8 af2[2];
            #pragma unroll
            for (int m = 0; m < 2; m++) {
                int trow = thm + m * 16 + lr;
                af2[m] = *(const bf16x8*)((const char*)Hs + trow * 128 + ((slot ^ (trow & 7)) << 4));
            }
            #pragma unroll
            for (int nt = 0; nt < 8; nt++) {
                int orow = wn2 + nt * 16 + lr;
                bf16x8 b2 = *(const bf16x8*)((const char*)Wc + orow * 128 + ((slot ^ (orow & 7)) << 4));
                #pragma unroll
                for (int m = 0; m < 2; m++)
                    acc_o[m][nt] = __builtin_amdgcn_mfma_f32_16x16x32_bf16(af2[m], b2, acc_o[m][nt], 0, 0, 0);
            }
        }
    }
    #pragma unroll
    for (int m = 0; m < 2; m++)
        #pragma unroll
        for (int nt = 0; nt < 8; nt++)
            #pragma unroll
            for (int r = 0; r < 4; r++) {
                int row = bm + thm + m * 16 + lq * 4 + r;
                int col = wn2 + nt * 16 + lr;
                size_t off = (size_t)row * 256 + col;
                R[off] = f2bf(acc_o[m][nt][r] + bf2f(R[off]));
            }
}

// ---------------------------------------------------------------------------
// V transpose: Vtok[t][256] bf16 -> Vt[h][col][d(32)][l(160)] bf16
__global__ __launch_bounds__(256) void vtrans(const unsigned short* __restrict__ vtok,
                                              unsigned short* __restrict__ vt, int W) {
    const int col = blockIdx.x, h = blockIdx.y;
    __shared__ unsigned short t[160][34];
    const int tid = threadIdx.x;
    for (int i = tid; i < 160 * 16; i += 256) {
        int l = i >> 4, dp = i & 15;
        unsigned v = *(const unsigned*)(vtok + ((size_t)l * W + col) * 256 + h * 32 + dp * 2);
        *(unsigned*)&t[l][dp * 2] = v;
    }
    __syncthreads();
    unsigned short* dst = vt + (((size_t)h * W + col) * 32) * 160;
    for (int i = tid; i < 32 * 160; i += 256) {
        int d = i / 160, l = i - d * 160;
        dst[i] = t[l][d];
    }
}

// ---------------------------------------------------------------------------
// MFMA attention (verified round 4/5), bf16 in/out
__global__ __launch_bounds__(64) void attn_mfma(const unsigned short* __restrict__ qk,
                                                const unsigned short* __restrict__ vt,
                                                unsigned short* __restrict__ o, int W) {
    const int col = blockIdx.x;
    const int h = blockIdx.y;
    const int lane = threadIdx.x;
    const int lr = lane & 15, lq = lane >> 4;
    __shared__ __align__(16) unsigned short P_lds[16][168];

    bf16x8 kf[10];
    #pragma unroll
    for (int m = 0; m < 10; m++) {
        size_t t = (size_t)(m * 16 + lr) * W + col;
        kf[m] = *(const bf16x8*)(qk + t * 512 + 256 + h * 32 + lq * 8);
    }
    const unsigned short* vbase = vt + (((size_t)h * W + col) * 32) * 160;
    bf16x8 vf[2][5];
    #pragma unroll
    for (int md = 0; md < 2; md++)
        #pragma unroll
        for (int c = 0; c < 5; c++)
            vf[md][c] = *(const bf16x8*)(vbase + (size_t)(md * 16 + lr) * 160 + c * 32 + lq * 8);

    const float scale = 0.17677669529663687f;
    for (int n = 0; n < 10; n++) {
        const int q = n * 16 + lr;
        bf16x8 qf = *(const bf16x8*)(qk + ((size_t)q * W + col) * 512 + h * 32 + lq * 8);
        f32x4 p[10];
        #pragma unroll
        for (int m = 0; m < 10; m++)
            p[m] = __builtin_amdgcn_mfma_f32_16x16x32_bf16(kf[m], qf, (f32x4){0.f,0.f,0.f,0.f}, 0, 0, 0);
        const int b = lq * 4 - ((n & 1) * 16 + lr);
        float mx = -1e30f;
        #pragma unroll
        for (int m = 0; m < 10; m++) {
            #pragma unroll
            for (int r = 0; r < 4; r++) {
                int dd = b + (m & 1) * 16 + r;
                float s = ((unsigned)(dd + 5) <= 10u) ? p[m][r] : -1e30f;
                p[m][r] = s;
                mx = fmaxf(mx, s);
            }
        }
        mx = fmaxf(mx, __shfl_xor(mx, 16));
        mx = fmaxf(mx, __shfl_xor(mx, 32));
        float sum = 0.f;
        #pragma unroll
        for (int m = 0; m < 10; m++) {
            #pragma unroll
            for (int r = 0; r < 4; r++) {
                float e = __expf((p[m][r] - mx) * scale);
                p[m][r] = e;
                sum += e;
            }
        }
        sum += __shfl_xor(sum, 16);
        sum += __shfl_xor(sum, 32);
        #pragma unroll
        for (int m = 0; m < 10; m++) {
            ushort4 pk;
            pk.x = f2bf(p[m][0]); pk.y = f2bf(p[m][1]);
            pk.z = f2bf(p[m][2]); pk.w = f2bf(p[m][3]);
            *(ushort4*)&P_lds[lr][m * 16 + lq * 4] = pk;
        }
        f32x4 oa0 = (f32x4){0.f,0.f,0.f,0.f}, oa1 = (f32x4){0.f,0.f,0.f,0.f};
        #pragma unroll
        for (int c = 0; c < 5; c++) {
            bf16x8 pf = *(const bf16x8*)&P_lds[lr][c * 32 + lq * 8];
            oa0 = __builtin_amdgcn_mfma_f32_16x16x32_bf16(vf[0][c], pf, oa0, 0, 0, 0);
            oa1 = __builtin_amdgcn_mfma_f32_16x16x32_bf16(vf[1][c], pf, oa1, 0, 0, 0);
        }
        const float inv = 1.0f / sum;
        unsigned short* op = o + ((size_t)q * W + col) * 256 + h * 32;
        ushort4 s0, s1;
        s0.x = f2bf(oa0[0] * inv); s0.y = f2bf(oa0[1] * inv);
        s0.z = f2bf(oa0[2] * inv); s0.w = f2bf(oa0[3] * inv);
        s1.x = f2bf(oa1[0] * inv); s1.y = f2bf(oa1[1] * inv);
        s1.z = f2bf(oa1[2] * inv); s1.w = f2bf(oa1[3] * inv);
        *(ushort4*)(op + lq * 4)      = s0;
        *(ushort4*)(op + 16 + lq * 4) = s1;
    }
}

// ---------------------------------------------------------------------------
// conv as implicit MFMA GEMM (verified round 3)
__global__ __launch_bounds__(256) void conv_mfma(const unsigned short* __restrict__ xp,
                                                 const unsigned short* __restrict__ wb,
                                                 const float* __restrict__ res,
                                                 float* __restrict__ out, int bb0) {
    const int ptile = blockIdx.x;
    const int slice = blockIdx.y;
    const int lb = slice / 25, n = slice % 25;
    const int bb = bb0 + lb;
    const int y0 = ptile * 4;
    __shared__ unsigned short As[128 * 64];
    __shared__ unsigned short Bs[128 * 64];
    const int tid = threadIdx.x;
    const int lane = tid & 63, w = tid >> 6;
    const int wm = (w >> 1) * 64;
    const int wn = (w & 1) * 64;
    const int lr = lane & 15, lq = lane >> 4;
    const unsigned short* xs = xp + (size_t)slice * 1024 * 128;
    f32x4 acc[4][4];
    #pragma unroll
    for (int m = 0; m < 4; m++)
        #pragma unroll
        for (int nn = 0; nn < 4; nn++)
            acc[m][nn] = (f32x4){0.f, 0.f, 0.f, 0.f};

    for (int tap = 0; tap < 9; tap++) {
        const int dy = tap / 3 - 1, dx = tap % 3 - 1;
        for (int c0 = 0; c0 < 128; c0 += 64) {
            #pragma unroll
            for (int i = 0; i < 4; i++) {
                int id = tid + 256 * i;
                int row = id >> 3, cg = id & 7;
                int py = y0 + (row >> 5) + dy;
                int px = (row & 31) + dx;
                uint4 v = {0u, 0u, 0u, 0u};
                if ((unsigned)py < 32u && (unsigned)px < 32u)
                    v = *(const uint4*)(xs + ((size_t)(py * 32 + px) * 128 + c0 + cg * 8));
                int boff = row * 128 + ((cg * 16) ^ ((row & 7) << 4));
                *(uint4*)((char*)As + boff) = v;
            }
            #pragma unroll
            for (int i = 0; i < 4; i++) {
                int id = tid + 256 * i;
                int row = id >> 3, cg = id & 7;
                uint4 v = *(const uint4*)(wb + (((size_t)tap * 128 + row) * 128 + c0 + cg * 8));
                int boff = row * 128 + ((cg * 16) ^ ((row & 7) << 4));
                *(uint4*)((char*)Bs + boff) = v;
            }
            __syncthreads();
            #pragma unroll
            for (int ks = 0; ks < 2; ks++) {
                bf16x8 wf[4], xf[4];
                #pragma unroll
                for (int m = 0; m < 4; m++) {
                    int row = wm + m * 16 + lr;
                    int boff = row * 128 + ((ks * 64 + lq * 16) ^ ((row & 7) << 4));
                    wf[m] = *(const bf16x8*)((const char*)Bs + boff);
                }
                #pragma unroll
                for (int nn = 0; nn < 4; nn++) {
                    int row = wn + nn * 16 + lr;
                    int boff = row * 128 + ((ks * 64 + lq * 16) ^ ((row & 7) << 4));
                    xf[nn] = *(const bf16x8*)((const char*)As + boff);
                }
                #pragma unroll
                for (int m = 0; m < 4; m++)
                    #pragma unroll
                    for (int nn = 0; nn < 4; nn++)
                        acc[m][nn] = __builtin_amdgcn_mfma_f32_16x16x32_bf16(wf[m], xf[nn], acc[m][nn], 0, 0, 0);
            }
            __syncthreads();
        }
    }
    #pragma unroll
    for (int m = 0; m < 4; m++) {
        int co0 = wm + m * 16 + lq * 4;
        #pragma unroll
        for (int r = 0; r < 4; r++) {
            size_t rowoff = (((size_t)(bb * 128 + co0 + r) * 25 + n) * 1024) + ptile * 128;
            #pragma unroll
            for (int nn = 0; nn < 4; nn++) {
                int pix = wn + nn * 16 + lr;
                out[rowoff + pix] = acc[m][nn][r] + res[rowoff + pix];
            }
        }
    }
}

// ---------------------------------------------------------------------------
extern "C" void kernel_launch(void* const* d_in, const int* in_sizes, int n_in,
                              void* d_out, int out_size, void* d_ws, size_t ws_size,
                              hipStream_t stream) {
    (void)in_sizes; (void)n_in; (void)out_size;
    const float* buffer     = (const float*)d_in[0];
    const float* Win        = (const float*)d_in[1];
    const float* ln_w       = (const float*)d_in[2];
    const float* ln_b       = (const float*)d_in[3];
    const float* in_proj    = (const float*)d_in[4];
    const float* attn_out_w = (const float*)d_in[5];
    const float* ffn_ln_w   = (const float*)d_in[6];
    const float* ffn_ln_b   = (const float*)d_in[7];
    const float* ff1        = (const float*)d_in[8];
    const float* ff2        = (const float*)d_in[9];
    const float* Wout       = (const float*)d_in[10];
    const float* conv_w     = (const float*)d_in[11];
    float* out = (float*)d_out;
    float* ws  = (float*)d_ws;

    const size_t need2 = ((size_t)51200 * 960 + 368640) * 4;
    int NBB = (ws_size >= need2) ? 2 : 1;
    const int W = NBB * 160;
    const size_t T = (size_t)NBB * 25600;

    // layout (float-slot offsets); all bf16
    unsigned short* x0b   = (unsigned short*)ws;                 // T*128 bf16
    unsigned short* Abf   = (unsigned short*)(ws + T * 64);      // T*256 bf16 residual
    unsigned short* tnb   = (unsigned short*)(ws + T * 192);     // T*256 bf16
    float*          C     = ws + T * 320;                        // T*512 fl region
    unsigned short* QKtok = (unsigned short*)C;                  // T*512 bf16
    unsigned short* Vtok  = (unsigned short*)(C + T * 256);      // T*256 bf16
    unsigned short* Vt    = (unsigned short*)(C + T * 384);      // T*256 bf16
    unsigned short* xp    = (unsigned short*)C;                  // T*128 bf16
    unsigned short* Db    = (unsigned short*)(ws + T * 832);     // T*256 bf16
    unsigned short* wg    = (unsigned short*)(ws + T * 960);     // 589824 bf16
    unsigned short* wb    = (unsigned short*)(ws + T * 960 + 294912); // 147456 bf16

    const unsigned short* Winb  = wg;
    const unsigned short* Wqkvb = wg + 32768;            // 768 rows: [Wq;Wk;Wv]
    const unsigned short* Waob  = wg + 229376;
    const unsigned short* Wff1b = wg + 294912;
    const unsigned short* Wff2b = wg + 425984;
    const unsigned short* Woutb = wg + 557056;

    const int GM64 = (int)(T / 64);      // 800 (or 400), % 8 == 0

    conv_weights<<<2304, 256, 0, stream>>>(Win, in_proj, attn_out_w, ff1, ff2, Wout, wg);
    repack_w<<<576, 256, 0, stream>>>(conv_w, wb);

    for (int pass = 0; pass < 2; pass++) {
        const float* src = (pass == 0) ? buffer : out;
        for (int bb0 = 0; bb0 < 2; bb0 += NBB) {
            if (pass == 0) gather1<<<dim3(128, 25, NBB), 256, 0, stream>>>(src, x0b, W, bb0);
            else           gather2<<<dim3(128, 25, NBB), 256, 0, stream>>>(src, x0b, W, bb0);

            // tok = x0 @ Win^T (K=128) -> Abf ; tnb = LN(tok)  [fused]
            gemm_ln<<<GM64, 256, 0, stream>>>(x0b, Winb, nullptr, Abf, tnb, ln_w, ln_b, 128);
            // fused qk (tn) + v (tok) projections, K=256
            gemm_qkv<<<dim3(GM64, 12), 256, 0, stream>>>(tnb, Abf, Wqkvb, QKtok, Vtok);
            vtrans<<<dim3(W, 8), 256, 0, stream>>>(Vtok, Vt, W);
            attn_mfma<<<dim3(W, 8), 64, 0, stream>>>(QKtok, Vt, Db, W);
            // tok += ob @ attn_out_w^T (in-place) ; tnb = LN_ffn(tok)  [fused]
            gemm_ln<<<GM64, 256, 0, stream>>>(Db, Waob, Abf, Abf, tnb, ffn_ln_w, ffn_ln_b, 256);
            // fused FFN: Abf += relu(tnb @ ff1^T) @ ff2^T
            ffn_fused<<<GM64, 256, 0, stream>>>(tnb, Wff1b, Wff2b, Abf);
            // ot = tok @ Wout^T (N=128) -> fused scatter into xp (pixel-major)
            gemm_bf16<<<dim3(GM64, 2), 256, 0, stream>>>(Abf, Woutb, xp, nullptr, 128, 256, 0, pass + 1, W);

            conv_mfma<<<dim3(8, NBB * 25), 256, 0, stream>>>(
                xp, wb, (pass == 0) ? buffer : (const float*)out, out, bb0);
        }
    }
}

// Round 20
// 535.411 us; speedup vs baseline: 1.3478x; 1.0404x over previous
//
#include <hip/hip_runtime.h>
#include <math.h>
#include <stdint.h>

typedef __attribute__((ext_vector_type(8))) short bf16x8;
typedef __attribute__((ext_vector_type(4))) float f32x4;

static __device__ __forceinline__ unsigned short f2bf(float f) {
    unsigned u = __builtin_bit_cast(unsigned, f);
    unsigned r = u + 0x7fffu + ((u >> 16) & 1u);   // RNE
    return (unsigned short)(r >> 16);
}
static __device__ __forceinline__ float bf2f(unsigned short h) {
    return __builtin_bit_cast(float, ((unsigned)h) << 16);
}
// async global->LDS, 16B per lane; lds dest = uniform base + lane*16
static __device__ __forceinline__ void gload_lds16(const void* g, void* l) {
    __builtin_amdgcn_global_load_lds((const __attribute__((address_space(1))) unsigned int*)g,
                                     (__attribute__((address_space(3))) unsigned int*)l, 16, 0, 0);
}

// ---------------------------------------------------------------------------
// gather pass1: x0b[t'][cc] (bf16) = src[bb][cc][u*5+v][y][x]
__global__ __launch_bounds__(256) void gather1(const float* __restrict__ src,
                                               unsigned short* __restrict__ x0, int W, int bb0) {
    int cct = blockIdx.x & 3, y = blockIdx.x >> 2;
    int n = blockIdx.y; int u = n / 5, v = n % 5;
    int lb = blockIdx.z, bb = bb0 + lb;
    __shared__ float tile[32][33];
    int tx = threadIdx.x & 31, tg = threadIdx.x >> 5;
    const float* s = src + (((size_t)(bb * 128 + cct * 32) * 25 + n) * 32 + y) * 32;
    #pragma unroll
    for (int i = 0; i < 4; i++) {
        int cl = tg + 8 * i;
        tile[cl][tx] = s[(size_t)cl * 25600 + tx];
    }
    __syncthreads();
    unsigned short* d = x0 + ((size_t)(u * 32 + y) * W + lb * 160 + v * 32) * 128 + cct * 32;
    #pragma unroll
    for (int i = 0; i < 4; i++) {
        int xx = tg + 8 * i;
        d[(size_t)xx * 128 + tx] = f2bf(tile[tx][xx]);
    }
}

// gather pass2
__global__ __launch_bounds__(256) void gather2(const float* __restrict__ src,
                                               unsigned short* __restrict__ x0, int W, int bb0) {
    int cct = blockIdx.x & 3, x = blockIdx.x >> 2;
    int n = blockIdx.y; int u = n / 5, v = n % 5;
    int lb = blockIdx.z, bb = bb0 + lb;
    __shared__ float tile[32][33];
    int tx = threadIdx.x & 31, tg = threadIdx.x >> 5;
    const float* s = src + (((size_t)(bb * 128 + cct * 32) * 25 + n) * 32) * 32 + x;
    #pragma unroll
    for (int i = 0; i < 4; i++) {
        int cl = tg + 8 * i;
        tile[cl][tx] = s[(size_t)cl * 25600 + tx * 32];
    }
    __syncthreads();
    unsigned short* d = x0 + ((size_t)(v * 32 + x) * W + lb * 160 + u * 32) * 128 + cct * 32;
    #pragma unroll
    for (int i = 0; i < 4; i++) {
        int yy = tg + 8 * i;
        d[(size_t)yy * 128 + tx] = f2bf(tile[tx][yy]);
    }
}

// ---------------------------------------------------------------------------
// conv weight repack: conv_w[co][ci][tap(9)] f32 -> wb[tap][co][ci] bf16
__global__ __launch_bounds__(256) void repack_w(const float* __restrict__ cw,
                                                unsigned short* __restrict__ wb) {
    int g = blockIdx.x * 256 + threadIdx.x;
    int co = g / 1152;
    int rem = g - co * 1152;
    int ci = rem / 9, tap = rem - ci * 9;
    wb[((size_t)tap * 128 + co) * 128 + ci] = f2bf(cw[g]);
}

// GEMM weights -> one bf16 buffer (layout preserved [N][K])
__global__ __launch_bounds__(256) void conv_weights(const float* __restrict__ Win,
                                                    const float* __restrict__ in_proj,
                                                    const float* __restrict__ attn_out_w,
                                                    const float* __restrict__ ff1,
                                                    const float* __restrict__ ff2,
                                                    const float* __restrict__ Wout,
                                                    unsigned short* __restrict__ wg) {
    int g = blockIdx.x * 256 + threadIdx.x;      // 589824 total
    float v;
    if      (g < 32768)  v = Win[g];
    else if (g < 229376) v = in_proj[g - 32768];
    else if (g < 294912) v = attn_out_w[g - 229376];
    else if (g < 425984) v = ff1[g - 294912];
    else if (g < 557056) v = ff2[g - 425984];
    else                 v = Wout[g - 557056];
    wg[g] = f2bf(v);
}

// ---------------------------------------------------------------------------
// XCD/L2-aware block remap (requires gridDim.x % 8 == 0)
static __device__ __forceinline__ void xcd_remap(int& bxi, int& byi) {
    int d = blockIdx.x + gridDim.x * blockIdx.y;
    int s = d & 7;
    unsigned j = (unsigned)(d >> 3);
    unsigned ny = gridDim.y;
    int gm8 = (int)(gridDim.x >> 3);
    bxi = s * gm8 + (int)(j / ny);
    byi = (int)(j % ny);
}

// ---------------------------------------------------------------------------
// GEMM core 64x64: BK=32, 2-buffer global_load_lds pipeline (round-12 best).
// LDS 16KB -> ~8 blocks/CU. 16B-slot swizzle slot ^= (row>>1)&3.
static __device__ __forceinline__ void gemm_core64(const unsigned short* __restrict__ X,
                                                   const unsigned short* __restrict__ Wt,
                                                   int bm, int bnrow, int K,
                                                   unsigned short (&As)[2][64 * 32],
                                                   unsigned short (&Bs)[2][64 * 32],
                                                   f32x4 (&acc)[2][2]) {
    const int tid = threadIdx.x;
    const int lane = tid & 63, w = tid >> 6;
    const int wm = (w >> 1) * 32, wn = (w & 1) * 32;
    const int lr = lane & 15, lq = lane >> 4;
    #pragma unroll
    for (int m = 0; m < 2; m++)
        #pragma unroll
        for (int n = 0; n < 2; n++)
            acc[m][n] = (f32x4){0.f, 0.f, 0.f, 0.f};

    const int srow = tid >> 2, sslot = tid & 3;
    const int ssl = sslot ^ ((srow >> 1) & 3);
    auto STAGE = [&](int bsel, int k0) {
        gload_lds16(X  + (size_t)(bm + srow) * K + k0 + ssl * 8,
                    &As[bsel][tid * 8]);
        gload_lds16(Wt + (size_t)(bnrow + srow) * K + k0 + ssl * 8,
                    &Bs[bsel][tid * 8]);
    };

    const int nt = K >> 5;
    STAGE(0, 0);
    __syncthreads();
    int cur = 0;
    for (int t = 0; t < nt; ++t) {
        if (t + 1 < nt) STAGE(cur ^ 1, (t + 1) << 5);
        const char* Ab = (const char*)As[cur];
        const char* Bb = (const char*)Bs[cur];
        bf16x8 af[2], bf[2];
        #pragma unroll
        for (int m = 0; m < 2; m++) {
            int row = wm + m * 16 + lr;
            af[m] = *(const bf16x8*)(Ab + row * 64 + ((lq * 16) ^ (((row >> 1) & 3) << 4)));
        }
        #pragma unroll
        for (int n = 0; n < 2; n++) {
            int row = wn + n * 16 + lr;
            bf[n] = *(const bf16x8*)(Bb + row * 64 + ((lq * 16) ^ (((row >> 1) & 3) << 4)));
        }
        #pragma unroll
        for (int m = 0; m < 2; m++)
            #pragma unroll
            for (int n = 0; n < 2; n++)
                acc[m][n] = __builtin_amdgcn_mfma_f32_16x16x32_bf16(af[m], bf[n], acc[m][n], 0, 0, 0);
        if (t + 1 < nt) __syncthreads();
        cur ^= 1;
    }
}

// general GEMM: Y = X @ Wt^T (+Rb) (relu?), spass=1/2 fused scatter epilogue
__global__ __launch_bounds__(256) void gemm_bf16(const unsigned short* __restrict__ X,
                                                 const unsigned short* __restrict__ Wt,
                                                 unsigned short* __restrict__ Yb,
                                                 const unsigned short* __restrict__ Rb,
                                                 int N, int K, int relu, int spass, int W) {
    __shared__ unsigned short As[2][64 * 32];
    __shared__ unsigned short Bs[2][64 * 32];
    int bxi, byi;
    xcd_remap(bxi, byi);
    const int bm = bxi * 64, bn = byi * 64;
    f32x4 acc[2][2];
    gemm_core64(X, Wt, bm, bn, K, As, Bs, acc);

    const int lane = threadIdx.x & 63, w = threadIdx.x >> 6;
    const int wm = (w >> 1) * 32, wn = (w & 1) * 32;
    const int lr = lane & 15, lq = lane >> 4;
    #pragma unroll
    for (int m = 0; m < 2; m++) {
        #pragma unroll
        for (int r = 0; r < 4; r++) {
            int row = bm + wm + m * 16 + lq * 4 + r;
            size_t base;
            if (spass == 0) {
                base = (size_t)row * N;
            } else {
                int l = row / W, c = row - l * W;
                int lb = (c >= 160) ? 1 : 0, sp = c - lb * 160;
                int sl_, pix;
                if (spass == 1) { int u = l >> 5, y = l & 31, v = sp >> 5, x = sp & 31;
                                  sl_ = lb * 25 + u * 5 + v; pix = y * 32 + x; }
                else            { int v = l >> 5, x = l & 31, u = sp >> 5, y = sp & 31;
                                  sl_ = lb * 25 + u * 5 + v; pix = y * 32 + x; }
                base = ((size_t)sl_ * 1024 + pix) * 128;
            }
            #pragma unroll
            for (int n = 0; n < 2; n++) {
                int col = bn + wn + n * 16 + lr;
                float val = acc[m][n][r];
                if (Rb) val += bf2f(Rb[(size_t)row * N + col]);
                if (relu) val = fmaxf(val, 0.0f);
                Yb[base + col] = f2bf(val);
            }
        }
    }
}

// fused qk+v GEMM, M=128 x N=64 tiles (grid.y=12 keeps blocks plentiful:
// 400x12=4800). 2x MFMA per barrier vs 64x64; B-panel staged once per 128
// rows. LDS 24KB -> 6 blocks/CU. Same verified 2-buffer + swizzle pattern.
__global__ __launch_bounds__(256) void gemm_qkv(const unsigned short* __restrict__ tn,
                                                const unsigned short* __restrict__ tok,
                                                const unsigned short* __restrict__ Wqkv,
                                                unsigned short* __restrict__ QK,
                                                unsigned short* __restrict__ V) {
    __shared__ unsigned short As[2][128 * 32];   // 8KB each
    __shared__ unsigned short Bs[2][64 * 32];    // 4KB each
    int bxi, by;
    xcd_remap(bxi, by);
    const int bm = bxi * 128;
    const int bnrow = by * 64;
    const unsigned short* X = (by < 8) ? tn : tok;
    const int K = 256;

    const int tid = threadIdx.x;
    const int lane = tid & 63, w = tid >> 6;
    const int wm = (w >> 1) * 64, wn = (w & 1) * 32;
    const int lr = lane & 15, lq = lane >> 4;
    f32x4 acc[4][2];
    #pragma unroll
    for (int m = 0; m < 4; m++)
        #pragma unroll
        for (int n = 0; n < 2; n++)
            acc[m][n] = (f32x4){0.f, 0.f, 0.f, 0.f};

    const int srow = tid >> 2, sslot = tid & 3;
    auto STAGE = [&](int bsel, int k0) {
        #pragma unroll
        for (int c = 0; c < 2; ++c) {
            int row = c * 64 + srow;
            int ssl = sslot ^ ((row >> 1) & 3);
            gload_lds16(X + (size_t)(bm + row) * K + k0 + ssl * 8,
                        &As[bsel][c * 2048 + tid * 8]);
        }
        {
            int ssl = sslot ^ ((srow >> 1) & 3);
            gload_lds16(Wqkv + (size_t)(bnrow + srow) * K + k0 + ssl * 8,
                        &Bs[bsel][tid * 8]);
        }
    };

    const int nt = K >> 5;        // 8
    STAGE(0, 0);
    __syncthreads();
    int cur = 0;
    for (int t = 0; t < nt; ++t) {
        if (t + 1 < nt) STAGE(cur ^ 1, (t + 1) << 5);
        const char* Ab = (const char*)As[cur];
        const char* Bb = (const char*)Bs[cur];
        bf16x8 af[4], bf[2];
        #pragma unroll
        for (int m = 0; m < 4; m++) {
            int row = wm + m * 16 + lr;
            af[m] = *(const bf16x8*)(Ab + row * 64 + ((lq * 16) ^ (((row >> 1) & 3) << 4)));
        }
        #pragma unroll
        for (int n = 0; n < 2; n++) {
            int row = wn + n * 16 + lr;
            bf[n] = *(const bf16x8*)(Bb + row * 64 + ((lq * 16) ^ (((row >> 1) & 3) << 4)));
        }
        #pragma unroll
        for (int m = 0; m < 4; m++)
            #pragma unroll
            for (int n = 0; n < 2; n++)
                acc[m][n] = __builtin_amdgcn_mfma_f32_16x16x32_bf16(af[m], bf[n], acc[m][n], 0, 0, 0);
        if (t + 1 < nt) __syncthreads();
        cur ^= 1;
    }

    unsigned short* Yb = (by < 8) ? QK : V;
    const int N = (by < 8) ? 512 : 256;
    const int bn = (by < 8) ? by * 64 : (by - 8) * 64;
    #pragma unroll
    for (int m = 0; m < 4; m++) {
        #pragma unroll
        for (int r = 0; r < 4; r++) {
            int row = bm + wm + m * 16 + lq * 4 + r;
            #pragma unroll
            for (int n = 0; n < 2; n++) {
                int col = bn + wn + n * 16 + lr;
                Yb[(size_t)row * N + col] = f2bf(acc[m][n][r]);
            }
        }
    }
}

// ---------------------------------------------------------------------------
// Full-row GEMM (64 tok x 256 cols) with FUSED LayerNorm epilogue.
__global__ __launch_bounds__(256) void gemm_ln(const unsigned short* __restrict__ X,
                                               const unsigned short* __restrict__ Wt,
                                               const unsigned short* __restrict__ Rb,
                                               unsigned short* __restrict__ Yraw,
                                               unsigned short* __restrict__ Tn,
                                               const float* __restrict__ lnw,
                                               const float* __restrict__ lnb, int K) {
    __shared__ unsigned short As[2][64 * 32];     // 4KB each
    __shared__ unsigned short Bs[2][256 * 32];    // 16KB each
    __shared__ float red_s[64][2], red_q[64][2];  // 1KB
    const int tid = threadIdx.x;
    const int lane = tid & 63, w = tid >> 6;
    const int lr = lane & 15, lq = lane >> 4;
    const int thm = (w >> 1) * 32;                // token rows
    const int wn2 = (w & 1) * 128;                // col half
    const int bm = blockIdx.x * 64;

    f32x4 acc[2][8];
    #pragma unroll
    for (int m = 0; m < 2; m++)
        #pragma unroll
        for (int n = 0; n < 8; n++)
            acc[m][n] = (f32x4){0.f, 0.f, 0.f, 0.f};

    const int srow = tid >> 2, sslot = tid & 3;
    auto STAGE = [&](int bsel, int k0) {
        {   int ssl = sslot ^ ((srow >> 1) & 3);
            gload_lds16(X + (size_t)(bm + srow) * K + k0 + ssl * 8, &As[bsel][tid * 8]); }
        #pragma unroll
        for (int i = 0; i < 4; i++) {
            int row = i * 64 + srow;
            int ssl = sslot ^ ((row >> 1) & 3);
            gload_lds16(Wt + (size_t)row * K + k0 + ssl * 8, &Bs[bsel][(i * 256 + tid) * 8]);
        }
    };

    const int ntk = K >> 5;
    STAGE(0, 0);
    __syncthreads();
    int cur = 0;
    for (int t = 0; t < ntk; ++t) {
        if (t + 1 < ntk) STAGE(cur ^ 1, (t + 1) << 5);
        const char* Ab = (const char*)As[cur];
        const char* Bb = (const char*)Bs[cur];
        bf16x8 af[2], bf[8];
        #pragma unroll
        for (int m = 0; m < 2; m++) {
            int row = thm + m * 16 + lr;
            af[m] = *(const bf16x8*)(Ab + row * 64 + ((lq * 16) ^ (((row >> 1) & 3) << 4)));
        }
        #pragma unroll
        for (int n = 0; n < 8; n++) {
            int row = wn2 + n * 16 + lr;
            bf[n] = *(const bf16x8*)(Bb + row * 64 + ((lq * 16) ^ (((row >> 1) & 3) << 4)));
        }
        #pragma unroll
        for (int m = 0; m < 2; m++)
            #pragma unroll
            for (int n = 0; n < 8; n++)
                acc[m][n] = __builtin_amdgcn_mfma_f32_16x16x32_bf16(af[m], bf[n], acc[m][n], 0, 0, 0);
        if (t + 1 < ntk) __syncthreads();
        cur ^= 1;
    }

    if (Rb) {
        #pragma unroll
        for (int m = 0; m < 2; m++)
            #pragma unroll
            for (int n = 0; n < 8; n++)
                #pragma unroll
                for (int r = 0; r < 4; r++) {
                    int row = bm + thm + m * 16 + lq * 4 + r;
                    int col = wn2 + n * 16 + lr;
                    acc[m][n][r] += bf2f(Rb[(size_t)row * 256 + col]);
                }
    }
    #pragma unroll
    for (int m = 0; m < 2; m++)
        #pragma unroll
        for (int r = 0; r < 4; r++) {
            float s = 0.f, q = 0.f;
            #pragma unroll
            for (int n = 0; n < 8; n++) {
                float v = acc[m][n][r];
                s += v; q += v * v;
            }
            #pragma unroll
            for (int off = 1; off < 16; off <<= 1) {
                s += __shfl_xor(s, off);
                q += __shfl_xor(q, off);
            }
            if (lr == 0) {
                int rt = thm + m * 16 + lq * 4 + r;
                red_s[rt][w & 1] = s;
                red_q[rt][w & 1] = q;
            }
        }
    __syncthreads();
    float wv[8], bv[8];
    #pragma unroll
    for (int n = 0; n < 8; n++) {
        wv[n] = lnw[wn2 + n * 16 + lr];
        bv[n] = lnb[wn2 + n * 16 + lr];
    }
    #pragma unroll
    for (int m = 0; m < 2; m++)
        #pragma unroll
        for (int r = 0; r < 4; r++) {
            int rt = thm + m * 16 + lq * 4 + r;
            float s = red_s[rt][0] + red_s[rt][1];
            float q = red_q[rt][0] + red_q[rt][1];
            float mu = s * (1.0f / 256.0f);
            float inv = rsqrtf(q * (1.0f / 256.0f) - mu * mu + 1e-5f);
            int row = bm + rt;
            #pragma unroll
            for (int n = 0; n < 8; n++) {
                int col = wn2 + n * 16 + lr;
                float v = acc[m][n][r];
                size_t off = (size_t)row * 256 + col;
                Yraw[off] = f2bf(v);
                Tn[off]   = f2bf((v - mu) * inv * wv[n] + bv[n]);
            }
        }
}

// ---------------------------------------------------------------------------
// Fused FFN v2 (round-15 verified best): R += relu(X @ W1^T) @ W2^T.
__global__ __launch_bounds__(256) void ffn_fused(const unsigned short* __restrict__ X,
                                                 const unsigned short* __restrict__ W1,
                                                 const unsigned short* __restrict__ W2,
                                                 unsigned short* __restrict__ R) {
    __shared__ unsigned short Wc[64 * 256];   // 32 KB (W1c [64][256] or W2c [256][64])
    __shared__ unsigned short Hs[64 * 64];    // 8 KB, row 128B, slot ^= row&7
    const int tid = threadIdx.x;
    const int lane = tid & 63, w = tid >> 6;
    const int lr = lane & 15, lq = lane >> 4;
    const int thm = (w >> 1) * 32;            // token rows for gemm2 A
    const int thb = (w & 1) * 32;             // token rows for gemm1 B (xf)
    const int hh  = (w >> 1) * 32;            // hidden rows for gemm1 A
    const int wn2 = (w & 1) * 128;            // out cols (gemm2)
    const int bm = blockIdx.x * 64;

    bf16x8 xf[2][8];
    #pragma unroll
    for (int nt = 0; nt < 2; nt++) {
        const unsigned short* xr = X + (size_t)(bm + thb + nt * 16 + lr) * 256 + lq * 8;
        #pragma unroll
        for (int ks = 0; ks < 8; ks++)
            xf[nt][ks] = *(const bf16x8*)(xr + ks * 32);
    }

    f32x4 acc_o[2][8];
    #pragma unroll
    for (int m = 0; m < 2; m++)
        #pragma unroll
        for (int nt = 0; nt < 8; nt++)
            acc_o[m][nt] = (f32x4){0.f, 0.f, 0.f, 0.f};

    for (int hk = 0; hk < 8; hk++) {
        if (hk) __syncthreads();
        #pragma unroll
        for (int i = 0; i < 8; i++) {
            int d = (w << 13) + (i << 10) + (lane << 4);
            int h = d >> 9, s = (d >> 4) & 31;
            int ss = s ^ (h & 7);
            gload_lds16(W1 + (size_t)(hk * 64 + h) * 256 + ss * 8,
                        (char*)Wc + (w << 13) + (i << 10));
        }
        __syncthreads();

        f32x4 acc1[2][2];
        #pragma unroll
        for (int mh = 0; mh < 2; mh++)
            #pragma unroll
            for (int nt = 0; nt < 2; nt++)
                acc1[mh][nt] = (f32x4){0.f, 0.f, 0.f, 0.f};
        #pragma unroll
        for (int ks = 0; ks < 8; ks++) {
            bf16x8 w1f[2];
            #pragma unroll
            for (int mh = 0; mh < 2; mh++) {
                int hrow = hh + mh * 16 + lr;
                int slot = ks * 4 + lq;
                w1f[mh] = *(const bf16x8*)((const char*)Wc + hrow * 512 + ((slot ^ (hrow & 7)) << 4));
            }
            #pragma unroll
            for (int mh = 0; mh < 2; mh++)
                #pragma unroll
                for (int nt = 0; nt < 2; nt++)
                    acc1[mh][nt] = __builtin_amdgcn_mfma_f32_16x16x32_bf16(w1f[mh], xf[nt][ks], acc1[mh][nt], 0, 0, 0);
        }
        #pragma unroll
        for (int mh = 0; mh < 2; mh++)
            #pragma unroll
            for (int nt = 0; nt < 2; nt++) {
                int hid0 = hh + mh * 16 + lq * 4;
                int tokr = thb + nt * 16 + lr;
                ushort4 pk;
                pk.x = f2bf(fmaxf(acc1[mh][nt][0], 0.0f));
                pk.y = f2bf(fmaxf(acc1[mh][nt][1], 0.0f));
                pk.z = f2bf(fmaxf(acc1[mh][nt][2], 0.0f));
                pk.w = f2bf(fmaxf(acc1[mh][nt][3], 0.0f));
                *(ushort4*)((char*)Hs + tokr * 128 +
                            (((hid0 >> 3) ^ (tokr & 7)) << 4) + (hid0 & 7) * 2) = pk;
            }
        __syncthreads();

        #pragma unroll
        for (int i = 0; i < 8; i++) {
            int d = (w << 13) + (i << 10) + (lane << 4);
            int o = d >> 7, s = (d >> 4) & 7;
            int ss = s ^ (o & 7);
            gload_lds16(W2 + (size_t)o * 512 + hk * 64 + ss * 8,
                        (char*)Wc + (w << 13) + (i << 10));
        }
        __syncthreads();

        #pragma unroll
        for (int ks = 0; ks < 2; ks++) {
            int slot = ks * 4 + lq;
            bf16x8 af2[2];
            #pragma unroll
            for (int m = 0; m < 2; m++) {
                int trow = thm + m * 16 + lr;
                af2[m] = *(const bf16x8*)((const char*)Hs + trow * 128 + ((slot ^ (trow & 7)) << 4));
            }
            #pragma unroll
            for (int nt = 0; nt < 8; nt++) {
                int orow = wn2 + nt * 16 + lr;
                bf16x8 b2 = *(const bf16x8*)((const char*)Wc + orow * 128 + ((slot ^ (orow & 7)) << 4));
                #pragma unroll
                for (int m = 0; m < 2; m++)
                    acc_o[m][nt] = __builtin_amdgcn_mfma_f32_16x16x32_bf16(af2[m], b2, acc_o[m][nt], 0, 0, 0);
            }
        }
    }
    #pragma unroll
    for (int m = 0; m < 2; m++)
        #pragma unroll
        for (int nt = 0; nt < 8; nt++)
            #pragma unroll
            for (int r = 0; r < 4; r++) {
                int row = bm + thm + m * 16 + lq * 4 + r;
                int col = wn2 + nt * 16 + lr;
                size_t off = (size_t)row * 256 + col;
                R[off] = f2bf(acc_o[m][nt][r] + bf2f(R[off]));
            }
}

// ---------------------------------------------------------------------------
// V transpose: Vtok[t][256] bf16 -> Vt[h][col][d(32)][l(160)] bf16
__global__ __launch_bounds__(256) void vtrans(const unsigned short* __restrict__ vtok,
                                              unsigned short* __restrict__ vt, int W) {
    const int col = blockIdx.x, h = blockIdx.y;
    __shared__ unsigned short t[160][34];
    const int tid = threadIdx.x;
    for (int i = tid; i < 160 * 16; i += 256) {
        int l = i >> 4, dp = i & 15;
        unsigned v = *(const unsigned*)(vtok + ((size_t)l * W + col) * 256 + h * 32 + dp * 2);
        *(unsigned*)&t[l][dp * 2] = v;
    }
    __syncthreads();
    unsigned short* dst = vt + (((size_t)h * W + col) * 32) * 160;
    for (int i = tid; i < 32 * 160; i += 256) {
        int d = i / 160, l = i - d * 160;
        dst[i] = t[l][d];
    }
}

// ---------------------------------------------------------------------------
// MFMA attention (verified round 4/5), bf16 in/out
__global__ __launch_bounds__(64) void attn_mfma(const unsigned short* __restrict__ qk,
                                                const unsigned short* __restrict__ vt,
                                                unsigned short* __restrict__ o, int W) {
    const int col = blockIdx.x;
    const int h = blockIdx.y;
    const int lane = threadIdx.x;
    const int lr = lane & 15, lq = lane >> 4;
    __shared__ __align__(16) unsigned short P_lds[16][168];

    bf16x8 kf[10];
    #pragma unroll
    for (int m = 0; m < 10; m++) {
        size_t t = (size_t)(m * 16 + lr) * W + col;
        kf[m] = *(const bf16x8*)(qk + t * 512 + 256 + h * 32 + lq * 8);
    }
    const unsigned short* vbase = vt + (((size_t)h * W + col) * 32) * 160;
    bf16x8 vf[2][5];
    #pragma unroll
    for (int md = 0; md < 2; md++)
        #pragma unroll
        for (int c = 0; c < 5; c++)
            vf[md][c] = *(const bf16x8*)(vbase + (size_t)(md * 16 + lr) * 160 + c * 32 + lq * 8);

    const float scale = 0.17677669529663687f;
    for (int n = 0; n < 10; n++) {
        const int q = n * 16 + lr;
        bf16x8 qf = *(const bf16x8*)(qk + ((size_t)q * W + col) * 512 + h * 32 + lq * 8);
        f32x4 p[10];
        #pragma unroll
        for (int m = 0; m < 10; m++)
            p[m] = __builtin_amdgcn_mfma_f32_16x16x32_bf16(kf[m], qf, (f32x4){0.f,0.f,0.f,0.f}, 0, 0, 0);
        const int b = lq * 4 - ((n & 1) * 16 + lr);
        float mx = -1e30f;
        #pragma unroll
        for (int m = 0; m < 10; m++) {
            #pragma unroll
            for (int r = 0; r < 4; r++) {
                int dd = b + (m & 1) * 16 + r;
                float s = ((unsigned)(dd + 5) <= 10u) ? p[m][r] : -1e30f;
                p[m][r] = s;
                mx = fmaxf(mx, s);
            }
        }
        mx = fmaxf(mx, __shfl_xor(mx, 16));
        mx = fmaxf(mx, __shfl_xor(mx, 32));
        float sum = 0.f;
        #pragma unroll
        for (int m = 0; m < 10; m++) {
            #pragma unroll
            for (int r = 0; r < 4; r++) {
                float e = __expf((p[m][r] - mx) * scale);
                p[m][r] = e;
                sum += e;
            }
        }
        sum += __shfl_xor(sum, 16);
        sum += __shfl_xor(sum, 32);
        #pragma unroll
        for (int m = 0; m < 10; m++) {
            ushort4 pk;
            pk.x = f2bf(p[m][0]); pk.y = f2bf(p[m][1]);
            pk.z = f2bf(p[m][2]); pk.w = f2bf(p[m][3]);
            *(ushort4*)&P_lds[lr][m * 16 + lq * 4] = pk;
        }
        f32x4 oa0 = (f32x4){0.f,0.f,0.f,0.f}, oa1 = (f32x4){0.f,0.f,0.f,0.f};
        #pragma unroll
        for (int c = 0; c < 5; c++) {
            bf16x8 pf = *(const bf16x8*)&P_lds[lr][c * 32 + lq * 8];
            oa0 = __builtin_amdgcn_mfma_f32_16x16x32_bf16(vf[0][c], pf, oa0, 0, 0, 0);
            oa1 = __builtin_amdgcn_mfma_f32_16x16x32_bf16(vf[1][c], pf, oa1, 0, 0, 0);
        }
        const float inv = 1.0f / sum;
        unsigned short* op = o + ((size_t)q * W + col) * 256 + h * 32;
        ushort4 s0, s1;
        s0.x = f2bf(oa0[0] * inv); s0.y = f2bf(oa0[1] * inv);
        s0.z = f2bf(oa0[2] * inv); s0.w = f2bf(oa0[3] * inv);
        s1.x = f2bf(oa1[0] * inv); s1.y = f2bf(oa1[1] * inv);
        s1.z = f2bf(oa1[2] * inv); s1.w = f2bf(oa1[3] * inv);
        *(ushort4*)(op + lq * 4)      = s0;
        *(ushort4*)(op + 16 + lq * 4) = s1;
    }
}

// ---------------------------------------------------------------------------
// conv as implicit MFMA GEMM (verified round 3)
__global__ __launch_bounds__(256) void conv_mfma(const unsigned short* __restrict__ xp,
                                                 const unsigned short* __restrict__ wb,
                                                 const float* __restrict__ res,
                                                 float* __restrict__ out, int bb0) {
    const int ptile = blockIdx.x;
    const int slice = blockIdx.y;
    const int lb = slice / 25, n = slice % 25;
    const int bb = bb0 + lb;
    const int y0 = ptile * 4;
    __shared__ unsigned short As[128 * 64];
    __shared__ unsigned short Bs[128 * 64];
    const int tid = threadIdx.x;
    const int lane = tid & 63, w = tid >> 6;
    const int wm = (w >> 1) * 64;
    const int wn = (w & 1) * 64;
    const int lr = lane & 15, lq = lane >> 4;
    const unsigned short* xs = xp + (size_t)slice * 1024 * 128;
    f32x4 acc[4][4];
    #pragma unroll
    for (int m = 0; m < 4; m++)
        #pragma unroll
        for (int nn = 0; nn < 4; nn++)
            acc[m][nn] = (f32x4){0.f, 0.f, 0.f, 0.f};

    for (int tap = 0; tap < 9; tap++) {
        const int dy = tap / 3 - 1, dx = tap % 3 - 1;
        for (int c0 = 0; c0 < 128; c0 += 64) {
            #pragma unroll
            for (int i = 0; i < 4; i++) {
                int id = tid + 256 * i;
                int row = id >> 3, cg = id & 7;
                int py = y0 + (row >> 5) + dy;
                int px = (row & 31) + dx;
                uint4 v = {0u, 0u, 0u, 0u};
                if ((unsigned)py < 32u && (unsigned)px < 32u)
                    v = *(const uint4*)(xs + ((size_t)(py * 32 + px) * 128 + c0 + cg * 8));
                int boff = row * 128 + ((cg * 16) ^ ((row & 7) << 4));
                *(uint4*)((char*)As + boff) = v;
            }
            #pragma unroll
            for (int i = 0; i < 4; i++) {
                int id = tid + 256 * i;
                int row = id >> 3, cg = id & 7;
                uint4 v = *(const uint4*)(wb + (((size_t)tap * 128 + row) * 128 + c0 + cg * 8));
                int boff = row * 128 + ((cg * 16) ^ ((row & 7) << 4));
                *(uint4*)((char*)Bs + boff) = v;
            }
            __syncthreads();
            #pragma unroll
            for (int ks = 0; ks < 2; ks++) {
                bf16x8 wf[4], xf[4];
                #pragma unroll
                for (int m = 0; m < 4; m++) {
                    int row = wm + m * 16 + lr;
                    int boff = row * 128 + ((ks * 64 + lq * 16) ^ ((row & 7) << 4));
                    wf[m] = *(const bf16x8*)((const char*)Bs + boff);
                }
                #pragma unroll
                for (int nn = 0; nn < 4; nn++) {
                    int row = wn + nn * 16 + lr;
                    int boff = row * 128 + ((ks * 64 + lq * 16) ^ ((row & 7) << 4));
                    xf[nn] = *(const bf16x8*)((const char*)As + boff);
                }
                #pragma unroll
                for (int m = 0; m < 4; m++)
                    #pragma unroll
                    for (int nn = 0; nn < 4; nn++)
                        acc[m][nn] = __builtin_amdgcn_mfma_f32_16x16x32_bf16(wf[m], xf[nn], acc[m][nn], 0, 0, 0);
            }
            __syncthreads();
        }
    }
    #pragma unroll
    for (int m = 0; m < 4; m++) {
        int co0 = wm + m * 16 + lq * 4;
        #pragma unroll
        for (int r = 0; r < 4; r++) {
            size_t rowoff = (((size_t)(bb * 128 + co0 + r) * 25 + n) * 1024) + ptile * 128;
            #pragma unroll
            for (int nn = 0; nn < 4; nn++) {
                int pix = wn + nn * 16 + lr;
                out[rowoff + pix] = acc[m][nn][r] + res[rowoff + pix];
            }
        }
    }
}

// ---------------------------------------------------------------------------
extern "C" void kernel_launch(void* const* d_in, const int* in_sizes, int n_in,
                              void* d_out, int out_size, void* d_ws, size_t ws_size,
                              hipStream_t stream) {
    (void)in_sizes; (void)n_in; (void)out_size;
    const float* buffer     = (const float*)d_in[0];
    const float* Win        = (const float*)d_in[1];
    const float* ln_w       = (const float*)d_in[2];
    const float* ln_b       = (const float*)d_in[3];
    const float* in_proj    = (const float*)d_in[4];
    const float* attn_out_w = (const float*)d_in[5];
    const float* ffn_ln_w   = (const float*)d_in[6];
    const float* ffn_ln_b   = (const float*)d_in[7];
    const float* ff1        = (const float*)d_in[8];
    const float* ff2        = (const float*)d_in[9];
    const float* Wout       = (const float*)d_in[10];
    const float* conv_w     = (const float*)d_in[11];
    float* out = (float*)d_out;
    float* ws  = (float*)d_ws;

    const size_t need2 = ((size_t)51200 * 960 + 368640) * 4;
    int NBB = (ws_size >= need2) ? 2 : 1;
    const int W = NBB * 160;
    const size_t T = (size_t)NBB * 25600;

    // layout (float-slot offsets); all bf16
    unsigned short* x0b   = (unsigned short*)ws;                 // T*128 bf16
    unsigned short* Abf   = (unsigned short*)(ws + T * 64);      // T*256 bf16 residual
    unsigned short* tnb   = (unsigned short*)(ws + T * 192);     // T*256 bf16
    float*          C     = ws + T * 320;                        // T*512 fl region
    unsigned short* QKtok = (unsigned short*)C;                  // T*512 bf16
    unsigned short* Vtok  = (unsigned short*)(C + T * 256);      // T*256 bf16
    unsigned short* Vt    = (unsigned short*)(C + T * 384);      // T*256 bf16
    unsigned short* xp    = (unsigned short*)C;                  // T*128 bf16
    unsigned short* Db    = (unsigned short*)(ws + T * 832);     // T*256 bf16
    unsigned short* wg    = (unsigned short*)(ws + T * 960);     // 589824 bf16
    unsigned short* wb    = (unsigned short*)(ws + T * 960 + 294912); // 147456 bf16

    const unsigned short* Winb  = wg;
    const unsigned short* Wqkvb = wg + 32768;            // 768 rows: [Wq;Wk;Wv]
    const unsigned short* Waob  = wg + 229376;
    const unsigned short* Wff1b = wg + 294912;
    const unsigned short* Wff2b = wg + 425984;
    const unsigned short* Woutb = wg + 557056;

    const int GM64  = (int)(T / 64);     // 800 (or 400), % 8 == 0
    const int GM128 = (int)(T / 128);    // 400 (or 200), % 8 == 0

    conv_weights<<<2304, 256, 0, stream>>>(Win, in_proj, attn_out_w, ff1, ff2, Wout, wg);
    repack_w<<<576, 256, 0, stream>>>(conv_w, wb);

    for (int pass = 0; pass < 2; pass++) {
        const float* src = (pass == 0) ? buffer : out;
        for (int bb0 = 0; bb0 < 2; bb0 += NBB) {
            if (pass == 0) gather1<<<dim3(128, 25, NBB), 256, 0, stream>>>(src, x0b, W, bb0);
            else           gather2<<<dim3(128, 25, NBB), 256, 0, stream>>>(src, x0b, W, bb0);

            // tok = x0 @ Win^T (K=128) -> Abf ; tnb = LN(tok)  [fused]
            gemm_ln<<<GM64, 256, 0, stream>>>(x0b, Winb, nullptr, Abf, tnb, ln_w, ln_b, 128);
            // fused qk (tn) + v (tok) projections, K=256, M=128 tiles
            gemm_qkv<<<dim3(GM128, 12), 256, 0, stream>>>(tnb, Abf, Wqkvb, QKtok, Vtok);
            vtrans<<<dim3(W, 8), 256, 0, stream>>>(Vtok, Vt, W);
            attn_mfma<<<dim3(W, 8), 64, 0, stream>>>(QKtok, Vt, Db, W);
            // tok += ob @ attn_out_w^T (in-place) ; tnb = LN_ffn(tok)  [fused]
            gemm_ln<<<GM64, 256, 0, stream>>>(Db, Waob, Abf, Abf, tnb, ffn_ln_w, ffn_ln_b, 256);
            // fused FFN: Abf += relu(tnb @ ff1^T) @ ff2^T
            ffn_fused<<<GM64, 256, 0, stream>>>(tnb, Wff1b, Wff2b, Abf);
            // ot = tok @ Wout^T (N=128) -> fused scatter into xp (pixel-major)
            gemm_bf16<<<dim3(GM64, 2), 256, 0, stream>>>(Abf, Woutb, xp, nullptr, 128, 256, 0, pass + 1, W);

            conv_mfma<<<dim3(8, NBB * 25), 256, 0, stream>>>(
                xp, wb, (pass == 0) ? buffer : (const float*)out, out, bb0);
        }
    }
}